// Round 13
// baseline (584.734 us; speedup 1.0000x reference)
//
#include <hip/hip_runtime.h>
#include <hip/hip_bf16.h>
#include <hip/hip_cooperative_groups.h>

namespace cg = cooperative_groups;

// Problem constants
#define TT 12608          // 4*B*N rows of hs
#define NC 3152           // B*N cache rows (= 16*197)
#define DIM 768
#define NPOS 197
#define NH 12
#define HD 64
#define FB_N 64           // 4*B
#define FF 3072
#define INNER_D 64
#define NCOLS 1536        // K cols + V cols combined

// stage-1 block ranges (3 weight transposes: wk, wv, wq)
#define NB_TW  1728       // 24*24*3
#define NB_TW1 48         // transpose w1: 24*2
#define NB_S1  (NB_TW + NB_TW1 + TT)
// stage-2 block ranges (inner first, then qfresh, then kv)
#define NB_INN 197        // ceil(TT/64)
#define NB_QF  6          // qfresh: 768/128
#define NB_KV  1248       // 8 * 13 * 12
#define NB_S2  (NB_INN + NB_QF + NB_KV)
// tail cooperative grid
#define NB_TAIL 384

typedef __bf16 bf16x8 __attribute__((ext_vector_type(8)));
typedef float f32x4 __attribute__((ext_vector_type(4)));

__device__ inline float wred_sum(float v){
  #pragma unroll
  for (int o = 32; o > 0; o >>= 1) v += __shfl_down(v, o, 64);
  return v;
}
__device__ inline float wred_max(float v){
  #pragma unroll
  for (int o = 32; o > 0; o >>= 1) v = fmaxf(v, __shfl_down(v, o, 64));
  return v;
}

// async global->LDS, 16B per lane
__device__ __forceinline__ void gl_lds16(const __bf16* g, __bf16* l) {
  __builtin_amdgcn_global_load_lds(
      (const __attribute__((address_space(1))) void*)g,
      (__attribute__((address_space(3))) void*)l, 16, 0, 0);
}

// ---------------------------------------------------------------------------
// K1: fused fresh-row flagging + reuse_map dtype detection.
__global__ void detect_flag_kernel(const int* __restrict__ gidx, const unsigned char* __restrict__ rm,
                                   int* __restrict__ flag, int* __restrict__ det)
{
  int g = blockIdx.x * 256 + threadIdx.x;
  int la = 0, lb = 0;
  if (g < TT) {
    int idx = gidx[g];
    if (idx >= NC) flag[idx - NC] = 1;
    unsigned char v = rm[g];
    if (v) { if (g & 3) la = 1; else lb = 1; }
  }
  unsigned long long ba = __ballot(la != 0), bb = __ballot(lb != 0);
  if ((threadIdx.x & 63) == 0) {
    if (ba) atomicOr(&det[0], 1);
    if (bb) atomicOr(&det[1], 1);
  }
}

// K1c: single-block dual exclusive scan; normalizes reuse_map inline.
__launch_bounds__(1024)
__global__ void scan_kernel(const int* __restrict__ flag, const unsigned char* __restrict__ rm,
                            const int* __restrict__ det, unsigned char* __restrict__ mask,
                            int* __restrict__ rowlist, int* __restrict__ remap,
                            int* __restrict__ mrowlist, int* __restrict__ mremap,
                            int* __restrict__ mc)
{
  __shared__ int wsumA[16], wsumB[16];
  __shared__ int baseA, baseB;
  int t = threadIdx.x, lane = t & 63, wv = t >> 6;
  int mode = (!det[0]) ? 0 : (det[1] ? 1 : 2); // 0=int32, 1=byte, 2=f32
  if (t == 0) { baseA = 0; baseB = 0; }
  __syncthreads();
  for (int start = 0; start < TT; start += 1024) {
    int i = start + t;
    int fA = 0, fB = 0;
    if (i < TT) {
      fA = flag[i];
      unsigned char mb_;
      if (mode == 0)      mb_ = ((const int*)rm)[i] != 0;
      else if (mode == 1) mb_ = rm[i] != 0;
      else                mb_ = ((const float*)rm)[i] != 0.0f;
      mask[i] = mb_;
      fB = mb_;
    }
    unsigned long long mbA = __ballot(fA != 0);
    unsigned long long mbB = __ballot(fB != 0);
    int rankA = __popcll(mbA & ((1ULL << lane) - 1ULL));
    int rankB = __popcll(mbB & ((1ULL << lane) - 1ULL));
    if (lane == 0) { wsumA[wv] = __popcll(mbA); wsumB[wv] = __popcll(mbB); }
    __syncthreads();
    int woffA = 0, woffB = 0;
    for (int w2 = 0; w2 < wv; w2++) { woffA += wsumA[w2]; woffB += wsumB[w2]; }
    if (fA) { int pos = baseA + woffA + rankA; rowlist[pos] = i; remap[i] = pos; }
    if (fB) { int pos = baseB + woffB + rankB; mrowlist[pos] = i; mremap[i] = pos; }
    __syncthreads();
    if (t == 0) {
      int ta = 0, tb = 0;
      for (int w2 = 0; w2 < 16; w2++) { ta += wsumA[w2]; tb += wsumB[w2]; }
      baseA += ta; baseB += tb;
    }
    __syncthreads();
  }
  if (t == 0) { mc[0] = baseA; mc[1] = baseB; }
}

// ---------------------------------------------------------------------------
// STAGE 1: fused {transpose wk/wv/wq} + {transpose w1} + {compact LN}
__launch_bounds__(256)
__global__ void stage1_kernel(const float* __restrict__ wk, const float* __restrict__ wvw,
                              const float* __restrict__ wq, const float* __restrict__ w1,
                              const float* __restrict__ hs,
                              const float* __restrict__ ln1g, const float* __restrict__ ln1b,
                              const int* __restrict__ rowlist, const int* __restrict__ mc,
                              __bf16* __restrict__ wcatT, __bf16* __restrict__ wqT,
                              __bf16* __restrict__ w1T, __bf16* __restrict__ xbf)
{
  __shared__ __align__(16) char pool[4352];
  int b = blockIdx.x, t = threadIdx.x;
  if (b < NB_TW) {
    float (*tile)[33] = (float(*)[33])pool;
    int bz = b / 576, rem = b % 576;
    int bx = rem % 24, by = rem / 24;
    int tx = t & 31, ty = t >> 5;
    const float* src = (bz == 0) ? wk : (bz == 1) ? wvw : wq;
    __bf16* dst = (bz == 0) ? wcatT : (bz == 1) ? (wcatT + (size_t)768 * DIM) : wqT;
    #pragma unroll
    for (int i = 0; i < 32; i += 8)
      tile[ty + i][tx] = src[(size_t)(by*32 + ty + i) * DIM + bx*32 + tx];
    __syncthreads();
    #pragma unroll
    for (int i = 0; i < 32; i += 8)
      dst[(size_t)(bx*32 + ty + i) * DIM + by*32 + tx] = (__bf16)tile[tx][ty + i];
    return;
  }
  if (b < NB_TW + NB_TW1) {
    float (*tile)[33] = (float(*)[33])pool;
    int rem = b - NB_TW;
    int bx = rem % 24, by = rem / 24;
    int tx = t & 31, ty = t >> 5;
    #pragma unroll
    for (int i = 0; i < 32; i += 8)
      tile[ty + i][tx] = w1[(size_t)(bx*32 + ty + i) * INNER_D + by*32 + tx];
    __syncthreads();
    #pragma unroll
    for (int i = 0; i < 32; i += 8)
      w1T[(size_t)(by*32 + ty + i) * DIM + bx*32 + tx] = (__bf16)tile[tx][ty + i];
    return;
  }
  int crow = b - NB_TW - NB_TW1;
  if (crow >= mc[0]) return;
  float* red = (float*)pool;
  int row = rowlist[crow];
  const float* x = hs + (size_t)row * DIM;
  float v0 = x[t], v1 = x[t + 256], v2 = x[t + 512];
  float s = wred_sum(v0 + v1 + v2);
  float q = wred_sum(v0*v0 + v1*v1 + v2*v2);
  int wv = t >> 6, ln = t & 63;
  if (ln == 0) { red[wv] = s; red[4 + wv] = q; }
  __syncthreads();
  float mean = (red[0]+red[1]+red[2]+red[3]) * (1.f/DIM);
  float var  = (red[4]+red[5]+red[6]+red[7]) * (1.f/DIM) - mean*mean;
  float rr = rsqrtf(var + 1e-5f);
  #pragma unroll
  for (int j = 0; j < 3; j++) {
    int c = t + j*256;
    float v = (j==0) ? v0 : (j==1) ? v1 : v2;
    xbf[(size_t)crow*DIM + c] = (__bf16)((v - mean) * rr * ln1g[c] + ln1b[c]);
  }
}

// ---------------------------------------------------------------------------
// STAGE 2: {inner MFMA GEMM} + {qfresh = gathered-xbf @ wqT} + {kv MFMA GEMM:
// BK=64, double-buffered LDS, counted vmcnt(8) pipeline, swizzled staging,
// coalesced C-store via LDS repack}
__launch_bounds__(256)
__global__ void stage2_kernel(const __bf16* __restrict__ xbf, const __bf16* __restrict__ wcatT,
                              const float* __restrict__ bk, const float* __restrict__ bv,
                              const float* __restrict__ dpp, const __bf16* __restrict__ w1T,
                              const __bf16* __restrict__ wqT,
                              const int* __restrict__ mrowlist, const int* __restrict__ mc,
                              const int* __restrict__ gidx, const int* __restrict__ remap,
                              __bf16* __restrict__ k_newc, __bf16* __restrict__ v_newc,
                              float* __restrict__ inner_c, float* __restrict__ qfresh)
{
  __shared__ __align__(16) char pool[65536];
  int b = blockIdx.x, t = threadIdx.x;
  int lane = t & 63, wid = t >> 6;
  int fr = lane & 15, fg = lane >> 4;

  if (b < NB_INN) {
    int mcnt = mc[1];
    int row0 = b * 64;
    if (row0 >= mcnt) return;
    typedef __bf16 (*tile_t)[40];
    tile_t As = (tile_t)pool;
    tile_t Bs = (tile_t)(pool + 5120);
    int* rlist = (int*)(pool + 10240);
    int wr = wid >> 1, wc = wid & 1;
    if (t < 64) rlist[t] = mrowlist[min(row0 + t, mcnt - 1)];
    __syncthreads();

    int lr = t >> 2, lc = (t & 3) << 3;
    const float* aG = dpp + (size_t)rlist[lr] * DIM + lc;
    const __bf16* bG = w1T + (size_t)lr * DIM + lc;

    f32x4 acc[2][2];
    #pragma unroll
    for (int m = 0; m < 2; m++)
      #pragma unroll
      for (int n = 0; n < 2; n++) acc[m][n] = (f32x4){0.f, 0.f, 0.f, 0.f};

    for (int k0 = 0; k0 < DIM; k0 += 32) {
      float4 a0 = *(const float4*)(aG + k0);
      float4 a1 = *(const float4*)(aG + k0 + 4);
      bf16x8 av;
      av[0] = (__bf16)a0.x; av[1] = (__bf16)a0.y; av[2] = (__bf16)a0.z; av[3] = (__bf16)a0.w;
      av[4] = (__bf16)a1.x; av[5] = (__bf16)a1.y; av[6] = (__bf16)a1.z; av[7] = (__bf16)a1.w;
      *(bf16x8*)&As[lr][lc] = av;
      *(bf16x8*)&Bs[lr][lc] = *(const bf16x8*)(bG + k0);
      __syncthreads();
      bf16x8 af[2], bb[2];
      #pragma unroll
      for (int m = 0; m < 2; m++) af[m] = *(const bf16x8*)&As[wr*32 + m*16 + fr][fg << 3];
      #pragma unroll
      for (int n = 0; n < 2; n++) bb[n] = *(const bf16x8*)&Bs[wc*32 + n*16 + fr][fg << 3];
      #pragma unroll
      for (int m = 0; m < 2; m++)
        #pragma unroll
        for (int n = 0; n < 2; n++)
          acc[m][n] = __builtin_amdgcn_mfma_f32_16x16x32_bf16(af[m], bb[n], acc[m][n], 0, 0, 0);
      __syncthreads();
    }

    #pragma unroll
    for (int m = 0; m < 2; m++) {
      #pragma unroll
      for (int n = 0; n < 2; n++) {
        int col = wc*32 + n*16 + fr;
        int orow = row0 + wr*32 + m*16 + fg*4;
        #pragma unroll
        for (int r = 0; r < 4; r++) {
          int rr = orow + r;
          if (rr < mcnt) {
            float x = acc[m][n][r];
            float u = 0.7978845608028654f * (x + 0.044715f * x * x * x);
            inner_c[(size_t)rr*INNER_D + col] = 0.5f * x * (1.0f + tanhf(u));
          }
        }
      }
    }
    return;
  }

  if (b < NB_INN + NB_QF) {
    int col0 = (b - NB_INN) * 128;
    typedef __bf16 (*tA_t)[40];
    tA_t As = (tA_t)pool;
    tA_t Bs = (tA_t)(pool + 5632);
    int* rl = (int*)(pool + 16384);
    int wr = wid >> 1, wc = wid & 1;
    if (t < FB_N) {
      int idx = gidx[t * NPOS];
      rl[t] = (idx >= NC) ? remap[idx - NC] : -1;
    }
    __syncthreads();

    f32x4 acc[2][4];
    #pragma unroll
    for (int m = 0; m < 2; m++)
      #pragma unroll
      for (int n = 0; n < 4; n++) acc[m][n] = (f32x4){0.f, 0.f, 0.f, 0.f};

    int ar = t >> 2, ac8 = (t & 3) << 3;
    int crow = rl[ar];
    for (int k0 = 0; k0 < DIM; k0 += 32) {
      bf16x8 av = {};
      if (crow >= 0) av = *(const bf16x8*)(xbf + (size_t)crow*DIM + k0 + ac8);
      *(bf16x8*)&As[ar][ac8] = av;
      #pragma unroll
      for (int q = 0; q < 2; q++) {
        int ch = t*2 + q;
        int brw = ch >> 2, bc8 = (ch & 3) << 3;
        *(bf16x8*)&Bs[brw][bc8] = *(const bf16x8*)(wqT + (size_t)(col0 + brw)*DIM + k0 + bc8);
      }
      __syncthreads();
      bf16x8 af[2], bb[4];
      #pragma unroll
      for (int m = 0; m < 2; m++) af[m] = *(const bf16x8*)&As[wr*32 + m*16 + fr][fg << 3];
      #pragma unroll
      for (int n = 0; n < 4; n++) bb[n] = *(const bf16x8*)&Bs[wc*64 + n*16 + fr][fg << 3];
      #pragma unroll
      for (int m = 0; m < 2; m++)
        #pragma unroll
        for (int n = 0; n < 4; n++)
          acc[m][n] = __builtin_amdgcn_mfma_f32_16x16x32_bf16(af[m], bb[n], acc[m][n], 0, 0, 0);
      __syncthreads();
    }
    #pragma unroll
    for (int m = 0; m < 2; m++) {
      #pragma unroll
      for (int n = 0; n < 4; n++) {
        int col = col0 + wc*64 + n*16 + fr;
        int row = wr*32 + m*16 + fg*4;
        #pragma unroll
        for (int r = 0; r < 4; r++)
          qfresh[(size_t)(row + r)*DIM + col] = acc[m][n][r];
      }
    }
    return;
  }

  // ---- kv GEMM: 128x128 tile, BK=64, dbuf + counted vmcnt pipeline
  {
    int Mc = mc[0];
    int npanels = (Mc + 127) >> 7;
    int b2 = b - NB_INN - NB_QF;
    int xcd = b2 & 7, s2 = b2 >> 3;
    int panel = (s2 / 12) * 8 + xcd;
    if (panel >= npanels) return;
    int col0 = (s2 % 12) * 128;
    int row0 = panel * 128;
    char* poolA0 = pool;
    char* poolA1 = pool + 16384;
    char* poolB0 = pool + 32768;
    char* poolB1 = pool + 49152;
    int wr = wid >> 1, wc = wid & 1;

    int tr = t >> 3;
    int tc = (t & 7) << 4;
    int cbp = tc ^ ((tr & 7) << 4);
    const __bf16* aP[4];
    const __bf16* bP[4];
    #pragma unroll
    for (int c2 = 0; c2 < 4; c2++) {
      int r = c2*32 + tr;
      aP[c2] = xbf + (size_t)min(row0 + r, Mc - 1) * DIM + (cbp >> 1);
      bP[c2] = wcatT + (size_t)(col0 + r) * DIM + (cbp >> 1);
    }

    int rA[4], rB[4];
    #pragma unroll
    for (int m = 0; m < 4; m++) { rA[m] = wr*64 + m*16 + fr; rB[m] = wc*64 + m*16 + fr; }
    int swzf = (fr & 7) << 4;

    f32x4 acc[4][4];
    #pragma unroll
    for (int m = 0; m < 4; m++)
      #pragma unroll
      for (int n = 0; n < 4; n++) acc[m][n] = (f32x4){0.f, 0.f, 0.f, 0.f};

    auto STAGE = [&](int s, char* dA, char* dB) {
      int k0 = s * 64;
      #pragma unroll
      for (int c2 = 0; c2 < 4; c2++) {
        gl_lds16(aP[c2] + k0, (__bf16*)(dA + c2*4096 + t*16));
        gl_lds16(bP[c2] + k0, (__bf16*)(dB + c2*4096 + t*16));
      }
    };

    STAGE(0, poolA0, poolB0);
    for (int s = 0; s < 12; s++) {
      char* curA = (s & 1) ? poolA1 : poolA0;
      char* curB = (s & 1) ? poolB1 : poolB0;
      if (s < 11) {
        STAGE(s + 1, (s & 1) ? poolA0 : poolA1, (s & 1) ? poolB0 : poolB1);
        asm volatile("s_waitcnt vmcnt(8)" ::: "memory");
      } else {
        asm volatile("s_waitcnt vmcnt(0)" ::: "memory");
      }
      __builtin_amdgcn_s_barrier();
      __builtin_amdgcn_sched_barrier(0);
      #pragma unroll
      for (int kk = 0; kk < 2; kk++) {
        int co = (kk*64 + (fg << 4)) ^ swzf;
        bf16x8 af[4], bb[4];
        #pragma unroll
        for (int m = 0; m < 4; m++) af[m] = *(const bf16x8*)(curA + rA[m]*128 + co);
        #pragma unroll
        for (int n = 0; n < 4; n++) bb[n] = *(const bf16x8*)(curB + rB[n]*128 + co);
        #pragma unroll
        for (int m = 0; m < 4; m++)
          #pragma unroll
          for (int n = 0; n < 4; n++)
            acc[m][n] = __builtin_amdgcn_mfma_f32_16x16x32_bf16(af[m], bb[n], acc[m][n], 0, 0, 0);
      }
      __builtin_amdgcn_sched_barrier(0);
      __builtin_amdgcn_s_barrier();
    }

    bool isK = (col0 < 768);
    const float* bias = isK ? bk : bv;
    __bf16* dst = isK ? k_newc : v_newc;
    int cbase = isK ? col0 : col0 - 768;
    __bf16* Ct = (__bf16*)pool;
    #pragma unroll
    for (int h = 0; h < 2; h++) {
      __syncthreads();
      if (wr == h) {
        #pragma unroll
        for (int n = 0; n < 4; n++) {
          int col = wc*64 + n*16 + fr;
          float bc = bias[cbase + col];
          #pragma unroll
          for (int m = 0; m < 4; m++) {
            int rl2 = m*16 + fg*4;
            #pragma unroll
            for (int r = 0; r < 4; r++)
              Ct[(rl2 + r)*128 + col] = (__bf16)(acc[m][n][r] + bc);
          }
        }
      }
      __syncthreads();
      #pragma unroll
      for (int c2 = 0; c2 < 4; c2++) {
        int o = c2*4096 + t*16;
        int rl2 = o >> 8;
        int cb = o & 255;
        int grow = row0 + h*64 + rl2;
        if (grow < Mc)
          *(uint4*)(dst + (size_t)grow*DIM + cbase + (cb >> 1)) = *(const uint4*)((char*)Ct + o);
      }
    }
  }
}

// ---------------------------------------------------------------------------
// K6: per (f,b): h_cls row, qbase row.
__launch_bounds__(256)
__global__ void cls_gather_kernel(const float* __restrict__ hs, const float* __restrict__ hqkv,
                                  const float* __restrict__ bq,
                                  const float* __restrict__ w2, const float* __restrict__ inner_c,
                                  const int* __restrict__ gidx, const unsigned char* __restrict__ mask,
                                  const int* __restrict__ mremap,
                                  float* __restrict__ h_cls, float* __restrict__ qbase)
{
  int fb = blockIdx.x, t = threadIdx.x;
  int g0 = fb * NPOS;
  int idx = gidx[g0];
  int m = mask[g0];
  const float* q_cache = hqkv + (size_t)NC * DIM;
  __shared__ float inn[INNER_D];
  if (t < INNER_D) inn[t] = m ? inner_c[(size_t)mremap[g0]*INNER_D + t] : 0.f;
  __syncthreads();
  bool fresh = idx >= NC;
  for (int c = t; c < DIM; c += 256) {
    float hv = fresh ? hs[(size_t)(idx - NC)*DIM + c] : hqkv[(size_t)idx*DIM + c];
    float qb = fresh ? bq[c] : q_cache[(size_t)idx*DIM + c];
    if (m) {
      float hd = 0.f, qd = 0.f;
      #pragma unroll 8
      for (int j = 0; j < INNER_D; j++) {
        float iv = inn[j];
        hd += iv * w2[(size_t)j*FF + c];
        qd += iv * w2[(size_t)j*FF + DIM + c];
      }
      hv += hd; qb += qd;
    }
    h_cls[(size_t)fb*DIM + c] = hv;
    qbase[(size_t)fb*DIM + c] = qb;
  }
}

// ---------------------------------------------------------------------------
// K8: CLS-row attention, 512 threads (8 waves), quad-dot gathers.
__launch_bounds__(512)
__global__ void attn_cls_kernel(const float* __restrict__ hqkv, const __bf16* __restrict__ k_newc,
                                const __bf16* __restrict__ v_newc, const float* __restrict__ w2,
                                const float* __restrict__ inner_c, const int* __restrict__ gidx,
                                const unsigned char* __restrict__ mask, const int* __restrict__ remap,
                                const int* __restrict__ mremap,
                                const float* __restrict__ qbase, const float* __restrict__ qfresh,
                                float* __restrict__ pre_cls)
{
  int bid = blockIdx.x;
  int fb = bid / NH, h = bid % NH;
  int t = threadIdx.x;
  int lane = t & 63, wv = t >> 6;
  const float* k_cache = hqkv + (size_t)2 * NC * DIM;
  const float* v_cache = hqkv + (size_t)3 * NC * DIM;
  __shared__ float q0[HD], w2q[INNER_D], tj[INNER_D];
  __shared__ float p[200];
  __shared__ int sidx[200];
  __shared__ int smg[200];
  __shared__ float red[16];
  __shared__ float pacc[8][64];
  if (t < HD) {
    size_t qoff = (size_t)fb*DIM + h*HD + t;
    q0[t] = (qbase[qoff] + qfresh[qoff]) * 0.125f;
  }
  int tt = t - 64;
  if (tt >= 0 && tt < NPOS) {
    int g = fb * NPOS + tt;
    int idx = gidx[g];
    if (idx >= NC) idx = NC + remap[idx - NC];
    sidx[tt] = idx;
    smg[tt] = mask[g] ? mremap[g] : -1;
  }
  __syncthreads();
  {
    int j = t >> 3, dg = t & 7;
    const float* wr = w2 + (size_t)j*FF + 2*DIM + h*HD + dg*8;
    float4 a = *(const float4*)wr, b = *(const float4*)(wr + 4);
    const float* q = &q0[dg*8];
    float s = a.x*q[0] + a.y*q[1] + a.z*q[2] + a.w*q[3]
            + b.x*q[4] + b.y*q[5] + b.z*q[6] + b.w*q[7];
    s += __shfl_xor(s, 1); s += __shfl_xor(s, 2); s += __shfl_xor(s, 4);
    if (dg == 0) w2q[j] = s;
  }
  __syncthreads();
  #pragma unroll
  for (int it = 0; it < 4; it++) {
    int n = it*64 + wv*8 + (lane >> 3);
    int dg = lane & 7;
    if (n < NPOS) {
      int idx = sidx[n], mg = smg[n];
      const float* q = &q0[dg*8];
      float s = 0.f;
      if (idx >= NC) {
        bf16x8 kv = *(const bf16x8*)(k_newc + (size_t)(idx - NC)*DIM + h*HD + dg*8);
        #pragma unroll
        for (int j = 0; j < 8; j++) s += q[j] * (float)kv[j];
      } else {
        const float* kr = k_cache + (size_t)idx*DIM + h*HD + dg*8;
        float4 a = *(const float4*)kr, b = *(const float4*)(kr + 4);
        s = a.x*q[0] + a.y*q[1] + a.z*q[2] + a.w*q[3]
          + b.x*q[4] + b.y*q[5] + b.z*q[6] + b.w*q[7];
      }
      if (mg >= 0) {
        const float* ir = inner_c + (size_t)mg*INNER_D + dg*8;
        float4 a = *(const float4*)ir, b = *(const float4*)(ir + 4);
        const float* wq8 = &w2q[dg*8];
        s += a.x*wq8[0] + a.y*wq8[1] + a.z*wq8[2] + a.w*wq8[3]
           + b.x*wq8[4] + b.y*wq8[5] + b.z*wq8[6] + b.w*wq8[7];
      }
      s += __shfl_xor(s, 1); s += __shfl_xor(s, 2); s += __shfl_xor(s, 4);
      if (dg == 0) p[n] = s;
    }
  }
  __syncthreads();
  float lm = (t < NPOS) ? p[t] : -1e30f;
  lm = wred_max(lm);
  if (lane == 0) red[wv] = lm;
  __syncthreads();
  float mx = red[0];
  #pragma unroll
  for (int w = 1; w < 8; w++) mx = fmaxf(mx, red[w]);
  float lp = 0.f;
  if (t < NPOS) { lp = __expf(p[t] - mx); p[t] = lp; }
  float ls = wred_sum(lp);
  if (lane == 0) red[8 + wv] = ls;
  __syncthreads();
  float inv = red[8];
  #pragma unroll
  for (int w = 1; w < 8; w++) inv += red[8 + w];
  inv = 1.0f / inv;
  float tp = 0.f;
  for (int n = wv; n < NPOS; n += 8) {
    int mg = smg[n];
    if (mg >= 0) tp += p[n] * inner_c[(size_t)mg*INNER_D + lane];
  }
  pacc[wv][lane] = tp;
  __syncthreads();
  if (t < INNER_D) tj[t] = pacc[0][t] + pacc[1][t] + pacc[2][t] + pacc[3][t]
                         + pacc[4][t] + pacc[5][t] + pacc[6][t] + pacc[7][t];
  __syncthreads();
  float va = 0.f;
  for (int n = wv; n < NPOS; n += 8) {
    float pn = p[n];
    int idx = sidx[n];
    float vvv;
    if (idx >= NC) vvv = (float)v_newc[(size_t)(idx - NC)*DIM + h*HD + lane];
    else           vvv = v_cache[(size_t)idx*DIM + h*HD + lane];
    va += pn * vvv;
  }
  __syncthreads();
  pacc[wv][lane] = va;
  __syncthreads();
  if (t < HD) {
    float o = pacc[0][t] + pacc[1][t] + pacc[2][t] + pacc[3][t]
            + pacc[4][t] + pacc[5][t] + pacc[6][t] + pacc[7][t];
    const float* wv2 = w2 + 3*DIM + h*HD + t;
    float dd = 0.f;
    for (int j = 0; j < INNER_D; j++) dd += tj[j] * wv2[(size_t)j*FF];
    pre_cls[(size_t)fb*DIM + h*HD + t] = (o + dd) * inv;
  }
}

// ---------------------------------------------------------------------------
// TAIL (cooperative): wo-GEMM -> reduce+LN2 -> fc1-GEMM -> gelu -> fc2-GEMM -> final.
__device__ void pgemm_dev(const float* __restrict__ X, const float* __restrict__ W,
                          float* __restrict__ part, int N, int K, int kChunk,
                          int colb, int kb, float (*Xs)[68], int t)
{
  int c = t & 63;
  int rq = t >> 6;
  int col0 = colb * 64;
  int k0base = kb * kChunk;
  float acc[16];
  #pragma unroll
  for (int i = 0; i < 16; i++) acc[i] = 0.f;
  for (int k0 = k0base; k0 < k0base + kChunk; k0 += 64) {
    #pragma unroll
    for (int j = 0; j < 4; j++) {
      int v = t + 256*j;
      int rr = v >> 4, cc = (v & 15) << 2;
      *(float4*)&Xs[rr][cc] = *(const float4*)&X[(size_t)rr*K + k0 + cc];
    }
    __syncthreads();
    const float* Wp = W + (size_t)k0*N + col0 + c;
    #pragma unroll 4
    for (int kk = 0; kk < 64; kk += 4) {
      float w0 = Wp[(size_t)(kk+0)*N];
      float w1 = Wp[(size_t)(kk+1)*N];
      float w2 = Wp[(size_t)(kk+2)*N];
      float w3 = Wp[(size_t)(kk+3)*N];
      #pragma unroll
      for (int r = 0; r < 16; r++) {
        float4 xv = *(const float4*)&Xs[rq*16 + r][kk];
        acc[r] += xv.x*w0 + xv.y*w1 + xv.z*w2 + xv.w*w3;
      }
    }
    __syncthreads();
  }
  #pragma unroll
  for (int r = 0; r < 16; r++)
    part[((size_t)kb*64 + rq*16 + r)*N + col0 + c] = acc[r];
}

__launch_bounds__(256)
__global__ void tail_kernel(const float* __restrict__ precls, const float* __restrict__ wo,
                            const float* __restrict__ bo, const float* __restrict__ h_cls,
                            const float* __restrict__ g2, const float* __restrict__ b2,
                            const float* __restrict__ fc1w, const float* __restrict__ fc1b,
                            const float* __restrict__ fc2w, const float* __restrict__ fc2b,
                            float* __restrict__ out0, float* __restrict__ yln,
                            float* __restrict__ t1, float* __restrict__ partW,
                            float* __restrict__ partF1, float* __restrict__ partF2,
                            float* __restrict__ dout)
{
  cg::grid_group grid = cg::this_grid();
  __shared__ __align__(16) float Xs[64][68];
  __shared__ float red2[8];
  int b = blockIdx.x, t = threadIdx.x;

  // P1: partW = precls @ wo   (12 col-tiles x 12 ksplits)
  if (b < 144) pgemm_dev(precls, wo, partW, DIM, DIM, 64, b % 12, b / 12, Xs, t);
  __threadfence();
  grid.sync();

  // P2: out0 = h_cls + sum(partW) + bo ; yln = LN2(out0)   (64 rows)
  if (b < FB_N) {
    int row = b;
    float v[3];
    #pragma unroll
    for (int j = 0; j < 3; j++) {
      int c = t + j*256;
      float s = h_cls[(size_t)row*DIM + c] + bo[c];
      #pragma unroll
      for (int ks = 0; ks < 12; ks++) s += partW[((size_t)ks*FB_N + row)*DIM + c];
      v[j] = s;
      out0[(size_t)row*DIM + c] = s;
    }
    float sm = wred_sum(v[0] + v[1] + v[2]);
    float sq = wred_sum(v[0]*v[0] + v[1]*v[1] + v[2]*v[2]);
    int wv = t >> 6, ln = t & 63;
    if (ln == 0) { red2[wv] = sm; red2[4 + wv] = sq; }
    __syncthreads();
    float mean = (red2[0]+red2[1]+red2[2]+red2[3]) * (1.f/DIM);
    float var  = (red2[4]+red2[5]+red2[6]+red2[7]) * (1.f/DIM) - mean*mean;
    float rr = rsqrtf(var + 1e-5f);
    #pragma unroll
    for (int j = 0; j < 3; j++) {
      int c = t + j*256;
      yln[(size_t)row*DIM + c] = (v[j] - mean) * rr * g2[c] + b2[c];
    }
  }
  __threadfence();
  grid.sync();

  // P3: partF1 = yln @ fc1w   (48 col-tiles x 6 ksplits)
  if (b < 288) pgemm_dev(yln, fc1w, partF1, FF, DIM, 128, b % 48, b / 48, Xs, t);
  __threadfence();
  grid.sync();

  // P4: t1 = quick_gelu(sum(partF1) + fc1b)
  for (int i = b*256 + t; i < FB_N*FF; i += NB_TAIL*256) {
    int c = i % FF;
    float v = fc1b[c];
    #pragma unroll
    for (int s = 0; s < 6; s++) v += partF1[(size_t)s*FB_N*FF + i];
    t1[i] = v / (1.0f + __expf(-1.702f * v));
  }
  __threadfence();
  grid.sync();

  // P5: partF2 = t1 @ fc2w   (12 col-tiles x 24 ksplits)
  if (b < 288) pgemm_dev(t1, fc2w, partF2, DIM, FF, 128, b % 12, b / 12, Xs, t);
  __threadfence();
  grid.sync();

  // P6: dout = out0 + fc2b + sum(partF2)
  for (int i = b*256 + t; i < FB_N*DIM; i += NB_TAIL*256) {
    int c = i % DIM;
    float v = out0[i] + fc2b[c];
    #pragma unroll
    for (int s = 0; s < 24; s++) v += partF2[(size_t)s*FB_N*DIM + i];
    dout[i] = v;
  }
}

// ---------------------------------------------------------------------------
extern "C" void kernel_launch(void* const* d_in, const int* in_sizes, int n_in,
                              void* d_out, int out_size, void* d_ws, size_t ws_size,
                              hipStream_t stream)
{
  const float* hs   = (const float*)d_in[0];
  const float* dpp  = (const float*)d_in[1];
  const float* hqkv = (const float*)d_in[2];
  const float* ln1g = (const float*)d_in[3];
  const float* ln1b = (const float*)d_in[4];
  const float* wq   = (const float*)d_in[5];
  const float* bq   = (const float*)d_in[6];
  const float* wk   = (const float*)d_in[7];
  const float* bk   = (const float*)d_in[8];
  const float* wvw  = (const float*)d_in[9];
  const float* bv   = (const float*)d_in[10];
  const float* w1   = (const float*)d_in[11];
  const float* w2   = (const float*)d_in[12];
  const float* wo   = (const float*)d_in[13];
  const float* bo   = (const float*)d_in[14];
  const float* ln2g = (const float*)d_in[15];
  const float* ln2b = (const float*)d_in[16];
  const float* fc1w = (const float*)d_in[17];
  const float* fc1b = (const float*)d_in[18];
  const float* fc2w = (const float*)d_in[19];
  const float* fc2b = (const float*)d_in[20];
  const int*   gidx = (const int*)d_in[21];
  const unsigned char* rmap = (const unsigned char*)d_in[22];
  float* outp = (float*)d_out;

  char* ws = (char*)d_ws;
  size_t off = 0;
  auto alloc = [&](size_t bytes) { void* p = ws + off; off += (bytes + 255) & ~(size_t)255; return p; };
  unsigned char* mask = (unsigned char*)alloc(TT);
  int* flag     = (int*)alloc((size_t)TT * 4);   // contiguous with mc: one memset
  int* mc       = (int*)alloc(256);
  int* rowlist  = (int*)alloc((size_t)TT * 4);
  int* remap    = (int*)alloc((size_t)TT * 4);
  int* mrowlist = (int*)alloc((size_t)TT * 4);
  int* mremap   = (int*)alloc((size_t)TT * 4);
  __bf16* xbf    = (__bf16*)alloc((size_t)TT * DIM * 2);
  __bf16* wcatT  = (__bf16*)alloc((size_t)NCOLS * DIM * 2);
  __bf16* wqT    = (__bf16*)alloc((size_t)DIM * DIM * 2);
  __bf16* w1T    = (__bf16*)alloc((size_t)INNER_D * DIM * 2);
  __bf16* k_newc = (__bf16*)alloc((size_t)TT * DIM * 2);
  __bf16* v_newc = (__bf16*)alloc((size_t)TT * DIM * 2);
  float* inner_c = (float*)alloc((size_t)TT * INNER_D * 4);
  float* qfresh  = (float*)alloc((size_t)FB_N * DIM * 4);
  float* h_cls  = (float*)alloc((size_t)FB_N * DIM * 4);
  float* qbase  = (float*)alloc((size_t)FB_N * DIM * 4);
  float* precls = (float*)alloc((size_t)FB_N * DIM * 4);
  float* out0   = (float*)alloc((size_t)FB_N * DIM * 4);
  float* yln    = (float*)alloc((size_t)FB_N * DIM * 4);
  float* t1     = (float*)alloc((size_t)FB_N * FF * 4);
  float* partW  = (float*)alloc((size_t)12 * FB_N * DIM * 4);
  float* partF1 = (float*)alloc((size_t)6  * FB_N * FF  * 4);
  float* partF2 = (float*)alloc((size_t)24 * FB_N * DIM * 4);
  (void)ws_size; (void)in_sizes; (void)n_in; (void)out_size;

  hipMemsetAsync(flag, 0, (size_t)TT * 4 + 256, stream);
  detect_flag_kernel<<<(TT + 255) / 256, 256, 0, stream>>>(gidx, rmap, flag, mc + 2);
  scan_kernel<<<1, 1024, 0, stream>>>(flag, rmap, mc + 2, mask, rowlist, remap,
                                      mrowlist, mremap, mc);
  stage1_kernel<<<NB_S1, 256, 0, stream>>>(wk, wvw, wq, w1, hs, ln1g, ln1b, rowlist, mc,
                                           wcatT, wqT, w1T, xbf);
  stage2_kernel<<<NB_S2, 256, 0, stream>>>(xbf, wcatT, bk, bv, dpp, w1T, wqT, mrowlist, mc,
                                           gidx, remap, k_newc, v_newc, inner_c, qfresh);
  cls_gather_kernel<<<FB_N, 256, 0, stream>>>(hs, hqkv, bq, w2, inner_c, gidx, mask,
                                              mremap, h_cls, qbase);
  attn_cls_kernel<<<FB_N * NH, 512, 0, stream>>>(hqkv, k_newc, v_newc, w2, inner_c, gidx, mask,
                                                 remap, mremap, qbase, qfresh, precls);
  // TAIL: cooperative fusion of {wo-GEMM, LN2, fc1, gelu, fc2, final}
  void* kargs[] = {
    (void*)&precls, (void*)&wo, (void*)&bo, (void*)&h_cls, (void*)&ln2g, (void*)&ln2b,
    (void*)&fc1w, (void*)&fc1b, (void*)&fc2w, (void*)&fc2b,
    (void*)&out0, (void*)&yln, (void*)&t1, (void*)&partW, (void*)&partF1, (void*)&partF2,
    (void*)&outp
  };
  hipLaunchCooperativeKernel((const void*)tail_kernel, dim3(NB_TAIL), dim3(256),
                             kargs, 0, stream);
}

// Round 14
// 176.718 us; speedup vs baseline: 3.3088x; 3.3088x over previous
//
#include <hip/hip_runtime.h>
#include <hip/hip_bf16.h>

// Problem constants
#define TT 12608          // 4*B*N rows of hs
#define NC 3152           // B*N cache rows (= 16*197)
#define DIM 768
#define NPOS 197
#define NH 12
#define HD 64
#define FB_N 64           // 4*B
#define FF 3072
#define INNER_D 64
#define NCOLS 1536        // K cols + V cols combined

// stage-1 block ranges (3 weight transposes: wk, wv, wq)
#define NB_TW  1728       // 24*24*3
#define NB_TW1 48         // transpose w1: 24*2
#define NB_S1  (NB_TW + NB_TW1 + TT)
// stage-2 block ranges (512 threads/block; inner first, then qfresh, then kv)
#define NB_INN 99         // ceil(TT/128)
#define NB_QF  6          // qfresh: 768/128
#define NB_KV  1248       // 8 * 13 * 12
#define NB_S2  (NB_INN + NB_QF + NB_KV)

typedef __bf16 bf16x8 __attribute__((ext_vector_type(8)));
typedef float f32x4 __attribute__((ext_vector_type(4)));

__device__ inline float wred_sum(float v){
  #pragma unroll
  for (int o = 32; o > 0; o >>= 1) v += __shfl_down(v, o, 64);
  return v;
}
__device__ inline float wred_max(float v){
  #pragma unroll
  for (int o = 32; o > 0; o >>= 1) v = fmaxf(v, __shfl_down(v, o, 64));
  return v;
}

// async global->LDS, 16B per lane
__device__ __forceinline__ void gl_lds16(const __bf16* g, __bf16* l) {
  __builtin_amdgcn_global_load_lds(
      (const __attribute__((address_space(1))) void*)g,
      (__attribute__((address_space(3))) void*)l, 16, 0, 0);
}

// ---------------------------------------------------------------------------
// K1: fused fresh-row flagging + reuse_map dtype detection.
__global__ void detect_flag_kernel(const int* __restrict__ gidx, const unsigned char* __restrict__ rm,
                                   int* __restrict__ flag, int* __restrict__ det)
{
  int g = blockIdx.x * 256 + threadIdx.x;
  int la = 0, lb = 0;
  if (g < TT) {
    int idx = gidx[g];
    if (idx >= NC) flag[idx - NC] = 1;
    unsigned char v = rm[g];
    if (v) { if (g & 3) la = 1; else lb = 1; }
  }
  unsigned long long ba = __ballot(la != 0), bb = __ballot(lb != 0);
  if ((threadIdx.x & 63) == 0) {
    if (ba) atomicOr(&det[0], 1);
    if (bb) atomicOr(&det[1], 1);
  }
}

// K1c: single-block dual exclusive scan; normalizes reuse_map inline.
__launch_bounds__(1024)
__global__ void scan_kernel(const int* __restrict__ flag, const unsigned char* __restrict__ rm,
                            const int* __restrict__ det, unsigned char* __restrict__ mask,
                            int* __restrict__ rowlist, int* __restrict__ remap,
                            int* __restrict__ mrowlist, int* __restrict__ mremap,
                            int* __restrict__ mc)
{
  __shared__ int wsumA[16], wsumB[16];
  __shared__ int baseA, baseB;
  int t = threadIdx.x, lane = t & 63, wv = t >> 6;
  int mode = (!det[0]) ? 0 : (det[1] ? 1 : 2); // 0=int32, 1=byte, 2=f32
  if (t == 0) { baseA = 0; baseB = 0; }
  __syncthreads();
  for (int start = 0; start < TT; start += 1024) {
    int i = start + t;
    int fA = 0, fB = 0;
    if (i < TT) {
      fA = flag[i];
      unsigned char mb_;
      if (mode == 0)      mb_ = ((const int*)rm)[i] != 0;
      else if (mode == 1) mb_ = rm[i] != 0;
      else                mb_ = ((const float*)rm)[i] != 0.0f;
      mask[i] = mb_;
      fB = mb_;
    }
    unsigned long long mbA = __ballot(fA != 0);
    unsigned long long mbB = __ballot(fB != 0);
    int rankA = __popcll(mbA & ((1ULL << lane) - 1ULL));
    int rankB = __popcll(mbB & ((1ULL << lane) - 1ULL));
    if (lane == 0) { wsumA[wv] = __popcll(mbA); wsumB[wv] = __popcll(mbB); }
    __syncthreads();
    int woffA = 0, woffB = 0;
    for (int w2 = 0; w2 < wv; w2++) { woffA += wsumA[w2]; woffB += wsumB[w2]; }
    if (fA) { int pos = baseA + woffA + rankA; rowlist[pos] = i; remap[i] = pos; }
    if (fB) { int pos = baseB + woffB + rankB; mrowlist[pos] = i; mremap[i] = pos; }
    __syncthreads();
    if (t == 0) {
      int ta = 0, tb = 0;
      for (int w2 = 0; w2 < 16; w2++) { ta += wsumA[w2]; tb += wsumB[w2]; }
      baseA += ta; baseB += tb;
    }
    __syncthreads();
  }
  if (t == 0) { mc[0] = baseA; mc[1] = baseB; }
}

// ---------------------------------------------------------------------------
// STAGE 1: fused {transpose wk/wv/wq} + {transpose w1} + {compact LN}
__launch_bounds__(256)
__global__ void stage1_kernel(const float* __restrict__ wk, const float* __restrict__ wvw,
                              const float* __restrict__ wq, const float* __restrict__ w1,
                              const float* __restrict__ hs,
                              const float* __restrict__ ln1g, const float* __restrict__ ln1b,
                              const int* __restrict__ rowlist, const int* __restrict__ mc,
                              __bf16* __restrict__ wcatT, __bf16* __restrict__ wqT,
                              __bf16* __restrict__ w1T, __bf16* __restrict__ xbf)
{
  __shared__ __align__(16) char pool[4352];
  int b = blockIdx.x, t = threadIdx.x;
  if (b < NB_TW) {
    float (*tile)[33] = (float(*)[33])pool;
    int bz = b / 576, rem = b % 576;
    int bx = rem % 24, by = rem / 24;
    int tx = t & 31, ty = t >> 5;
    const float* src = (bz == 0) ? wk : (bz == 1) ? wvw : wq;
    __bf16* dst = (bz == 0) ? wcatT : (bz == 1) ? (wcatT + (size_t)768 * DIM) : wqT;
    #pragma unroll
    for (int i = 0; i < 32; i += 8)
      tile[ty + i][tx] = src[(size_t)(by*32 + ty + i) * DIM + bx*32 + tx];
    __syncthreads();
    #pragma unroll
    for (int i = 0; i < 32; i += 8)
      dst[(size_t)(bx*32 + ty + i) * DIM + by*32 + tx] = (__bf16)tile[tx][ty + i];
    return;
  }
  if (b < NB_TW + NB_TW1) {
    float (*tile)[33] = (float(*)[33])pool;
    int rem = b - NB_TW;
    int bx = rem % 24, by = rem / 24;
    int tx = t & 31, ty = t >> 5;
    #pragma unroll
    for (int i = 0; i < 32; i += 8)
      tile[ty + i][tx] = w1[(size_t)(bx*32 + ty + i) * INNER_D + by*32 + tx];
    __syncthreads();
    #pragma unroll
    for (int i = 0; i < 32; i += 8)
      w1T[(size_t)(by*32 + ty + i) * DIM + bx*32 + tx] = (__bf16)tile[tx][ty + i];
    return;
  }
  int crow = b - NB_TW - NB_TW1;
  if (crow >= mc[0]) return;
  float* red = (float*)pool;
  int row = rowlist[crow];
  const float* x = hs + (size_t)row * DIM;
  float v0 = x[t], v1 = x[t + 256], v2 = x[t + 512];
  float s = wred_sum(v0 + v1 + v2);
  float q = wred_sum(v0*v0 + v1*v1 + v2*v2);
  int wv = t >> 6, ln = t & 63;
  if (ln == 0) { red[wv] = s; red[4 + wv] = q; }
  __syncthreads();
  float mean = (red[0]+red[1]+red[2]+red[3]) * (1.f/DIM);
  float var  = (red[4]+red[5]+red[6]+red[7]) * (1.f/DIM) - mean*mean;
  float rr = rsqrtf(var + 1e-5f);
  #pragma unroll
  for (int j = 0; j < 3; j++) {
    int c = t + j*256;
    float v = (j==0) ? v0 : (j==1) ? v1 : v2;
    xbf[(size_t)crow*DIM + c] = (__bf16)((v - mean) * rr * ln1g[c] + ln1b[c]);
  }
}

// ---------------------------------------------------------------------------
// STAGE 2 (512 threads / 8 waves): {inner GEMM 128-row tiles} + {qfresh} +
// {kv GEMM 128x128 BK=64, dbuf + counted vmcnt(4), swizzled staging, LDS-repack store}
__launch_bounds__(512)
__global__ void stage2_kernel(const __bf16* __restrict__ xbf, const __bf16* __restrict__ wcatT,
                              const float* __restrict__ bk, const float* __restrict__ bv,
                              const float* __restrict__ dpp, const __bf16* __restrict__ w1T,
                              const __bf16* __restrict__ wqT,
                              const int* __restrict__ mrowlist, const int* __restrict__ mc,
                              const int* __restrict__ gidx, const int* __restrict__ remap,
                              __bf16* __restrict__ k_newc, __bf16* __restrict__ v_newc,
                              float* __restrict__ inner_c, float* __restrict__ qfresh)
{
  __shared__ __align__(16) char pool[65536];
  int b = blockIdx.x, t = threadIdx.x;
  int lane = t & 63, wid = t >> 6;          // 8 waves
  int fr = lane & 15, fg = lane >> 4;

  if (b < NB_INN) {
    // ---- inner GEMM over MASKED rows: 128x64 tile, full K=768, gelu epilogue
    int mcnt = mc[1];
    int row0 = b * 128;
    if (row0 >= mcnt) return;
    typedef __bf16 (*tA_t)[40];
    tA_t As = (tA_t)pool;                   // [128][40]
    tA_t Bs = (tA_t)(pool + 10240);         // [64][40]
    int* rlist = (int*)(pool + 15360);      // [128]
    int wr = wid >> 1, wc = wid & 1;        // 4x2 wave grid: per-wave 32x32
    if (t < 128) rlist[t] = mrowlist[min(row0 + t, mcnt - 1)];
    __syncthreads();

    int lr = t >> 2, lc = (t & 3) << 3;     // A: 128 rows, 4 thr/row
    const float* aG = dpp + (size_t)rlist[lr] * DIM + lc;
    int lrB = (t & 255) >> 2;               // B: 64 rows (t<256 stages)
    const __bf16* bG = w1T + (size_t)lrB * DIM + lc;

    f32x4 acc[2][2];
    #pragma unroll
    for (int m = 0; m < 2; m++)
      #pragma unroll
      for (int n = 0; n < 2; n++) acc[m][n] = (f32x4){0.f, 0.f, 0.f, 0.f};

    for (int k0 = 0; k0 < DIM; k0 += 32) {
      float4 a0 = *(const float4*)(aG + k0);
      float4 a1 = *(const float4*)(aG + k0 + 4);
      bf16x8 av;
      av[0] = (__bf16)a0.x; av[1] = (__bf16)a0.y; av[2] = (__bf16)a0.z; av[3] = (__bf16)a0.w;
      av[4] = (__bf16)a1.x; av[5] = (__bf16)a1.y; av[6] = (__bf16)a1.z; av[7] = (__bf16)a1.w;
      *(bf16x8*)&As[lr][lc] = av;
      if (t < 256) *(bf16x8*)&Bs[lrB][lc] = *(const bf16x8*)(bG + k0);
      __syncthreads();
      bf16x8 af[2], bb[2];
      #pragma unroll
      for (int m = 0; m < 2; m++) af[m] = *(const bf16x8*)&As[wr*32 + m*16 + fr][fg << 3];
      #pragma unroll
      for (int n = 0; n < 2; n++) bb[n] = *(const bf16x8*)&Bs[wc*32 + n*16 + fr][fg << 3];
      #pragma unroll
      for (int m = 0; m < 2; m++)
        #pragma unroll
        for (int n = 0; n < 2; n++)
          acc[m][n] = __builtin_amdgcn_mfma_f32_16x16x32_bf16(af[m], bb[n], acc[m][n], 0, 0, 0);
      __syncthreads();
    }

    #pragma unroll
    for (int m = 0; m < 2; m++) {
      #pragma unroll
      for (int n = 0; n < 2; n++) {
        int col = wc*32 + n*16 + fr;
        int orow = row0 + wr*32 + m*16 + fg*4;
        #pragma unroll
        for (int r = 0; r < 4; r++) {
          int rr = orow + r;
          if (rr < mcnt) {
            float x = acc[m][n][r];
            float u = 0.7978845608028654f * (x + 0.044715f * x * x * x);
            inner_c[(size_t)rr*INNER_D + col] = 0.5f * x * (1.0f + tanhf(u));
          }
        }
      }
    }
    return;
  }

  if (b < NB_INN + NB_QF) {
    // ---- qfresh: 64 CLS rows @ wqT, 64x128 tile, 2x4 wave grid (per-wave 32x32)
    int col0 = (b - NB_INN) * 128;
    typedef __bf16 (*tA_t)[40];
    tA_t As = (tA_t)pool;                   // [64][40]
    tA_t Bs = (tA_t)(pool + 5632);          // [128][40]
    int* rl = (int*)(pool + 16384);
    int wr = wid >> 2, wc = wid & 3;
    if (t < FB_N) {
      int idx = gidx[t * NPOS];
      rl[t] = (idx >= NC) ? remap[idx - NC] : -1;
    }
    __syncthreads();

    f32x4 acc[2][2];
    #pragma unroll
    for (int m = 0; m < 2; m++)
      #pragma unroll
      for (int n = 0; n < 2; n++) acc[m][n] = (f32x4){0.f, 0.f, 0.f, 0.f};

    int ar = (t & 255) >> 2, ac8 = (t & 3) << 3;   // A: t<256 stages 64 rows
    int crow = (t < 256) ? rl[ar] : -1;
    int brw = t >> 2, bc8 = (t & 3) << 3;          // B: all 512 stage 128 rows
    for (int k0 = 0; k0 < DIM; k0 += 32) {
      if (t < 256) {
        bf16x8 av = {};
        if (crow >= 0) av = *(const bf16x8*)(xbf + (size_t)crow*DIM + k0 + ac8);
        *(bf16x8*)&As[ar][ac8] = av;
      }
      *(bf16x8*)&Bs[brw][bc8] = *(const bf16x8*)(wqT + (size_t)(col0 + brw)*DIM + k0 + bc8);
      __syncthreads();
      bf16x8 af[2], bb[2];
      #pragma unroll
      for (int m = 0; m < 2; m++) af[m] = *(const bf16x8*)&As[wr*32 + m*16 + fr][fg << 3];
      #pragma unroll
      for (int n = 0; n < 2; n++) bb[n] = *(const bf16x8*)&Bs[wc*32 + n*16 + fr][fg << 3];
      #pragma unroll
      for (int m = 0; m < 2; m++)
        #pragma unroll
        for (int n = 0; n < 2; n++)
          acc[m][n] = __builtin_amdgcn_mfma_f32_16x16x32_bf16(af[m], bb[n], acc[m][n], 0, 0, 0);
      __syncthreads();
    }
    #pragma unroll
    for (int m = 0; m < 2; m++) {
      #pragma unroll
      for (int n = 0; n < 2; n++) {
        int col = col0 + wc*32 + n*16 + fr;
        int row = wr*32 + m*16 + fg*4;
        #pragma unroll
        for (int r = 0; r < 4; r++)
          qfresh[(size_t)(row + r)*DIM + col] = acc[m][n][r];
      }
    }
    return;
  }

  // ---- kv GEMM: 128x128 tile, BK=64, dbuf + counted vmcnt(4), 2x4 wave grid
  {
    int Mc = mc[0];
    int npanels = (Mc + 127) >> 7;
    int b2 = b - NB_INN - NB_QF;
    int xcd = b2 & 7, s2 = b2 >> 3;
    int panel = (s2 / 12) * 8 + xcd;
    if (panel >= npanels) return;
    int col0 = (s2 % 12) * 128;
    int row0 = panel * 128;
    char* poolA0 = pool;
    char* poolA1 = pool + 16384;
    char* poolB0 = pool + 32768;
    char* poolB1 = pool + 49152;
    int wr = wid >> 2, wc = wid & 3;        // per-wave 64 rows x 32 cols

    // staging: 512 thr x 2 chunks x 16B per matrix. chunk c2: row = c2*64 + (t>>3)
    int tr = t >> 3;
    int tc = (t & 7) << 4;
    int cbp = tc ^ ((tr & 7) << 4);         // swizzled SOURCE col ((c2*64+tr)&7 == tr&7)
    const __bf16* aP[2];
    const __bf16* bP[2];
    #pragma unroll
    for (int c2 = 0; c2 < 2; c2++) {
      int r = c2*64 + tr;
      aP[c2] = xbf + (size_t)min(row0 + r, Mc - 1) * DIM + (cbp >> 1);
      bP[c2] = wcatT + (size_t)(col0 + r) * DIM + (cbp >> 1);
    }

    int rA[4], rB[2];
    #pragma unroll
    for (int m = 0; m < 4; m++) rA[m] = wr*64 + m*16 + fr;
    #pragma unroll
    for (int n = 0; n < 2; n++) rB[n] = wc*32 + n*16 + fr;
    int swzf = (fr & 7) << 4;

    f32x4 acc[4][2];
    #pragma unroll
    for (int m = 0; m < 4; m++)
      #pragma unroll
      for (int n = 0; n < 2; n++) acc[m][n] = (f32x4){0.f, 0.f, 0.f, 0.f};

    auto STAGE = [&](int s, char* dA, char* dB) {
      int k0 = s * 64;
      #pragma unroll
      for (int c2 = 0; c2 < 2; c2++) {
        gl_lds16(aP[c2] + k0, (__bf16*)(dA + c2*8192 + t*16));
        gl_lds16(bP[c2] + k0, (__bf16*)(dB + c2*8192 + t*16));
      }
    };

    STAGE(0, poolA0, poolB0);
    for (int s = 0; s < 12; s++) {
      char* curA = (s & 1) ? poolA1 : poolA0;
      char* curB = (s & 1) ? poolB1 : poolB0;
      if (s < 11) {
        STAGE(s + 1, (s & 1) ? poolA0 : poolA1, (s & 1) ? poolB0 : poolB1);
        asm volatile("s_waitcnt vmcnt(4)" ::: "memory");   // prev tile's 4 loads done
      } else {
        asm volatile("s_waitcnt vmcnt(0)" ::: "memory");
      }
      __builtin_amdgcn_s_barrier();
      __builtin_amdgcn_sched_barrier(0);
      #pragma unroll
      for (int kk = 0; kk < 2; kk++) {
        int co = (kk*64 + (fg << 4)) ^ swzf;
        bf16x8 af[4], bb[2];
        #pragma unroll
        for (int m = 0; m < 4; m++) af[m] = *(const bf16x8*)(curA + rA[m]*128 + co);
        #pragma unroll
        for (int n = 0; n < 2; n++) bb[n] = *(const bf16x8*)(curB + rB[n]*128 + co);
        #pragma unroll
        for (int m = 0; m < 4; m++)
          #pragma unroll
          for (int n = 0; n < 2; n++)
            acc[m][n] = __builtin_amdgcn_mfma_f32_16x16x32_bf16(af[m], bb[n], acc[m][n], 0, 0, 0);
      }
      __builtin_amdgcn_sched_barrier(0);
      __builtin_amdgcn_s_barrier();
    }

    // epilogue: per 64-row half, repack C in LDS, coalesced uint4 stores
    bool isK = (col0 < 768);
    const float* bias = isK ? bk : bv;
    __bf16* dst = isK ? k_newc : v_newc;
    int cbase = isK ? col0 : col0 - 768;
    __bf16* Ct = (__bf16*)pool;             // [64][128]
    #pragma unroll
    for (int h = 0; h < 2; h++) {
      __syncthreads();
      if (wr == h) {
        #pragma unroll
        for (int n = 0; n < 2; n++) {
          int col = wc*32 + n*16 + fr;
          float bc = bias[cbase + col];
          #pragma unroll
          for (int m = 0; m < 4; m++) {
            int rl2 = m*16 + fg*4;
            #pragma unroll
            for (int r = 0; r < 4; r++)
              Ct[(rl2 + r)*128 + col] = (__bf16)(acc[m][n][r] + bc);
          }
        }
      }
      __syncthreads();
      #pragma unroll
      for (int c2 = 0; c2 < 2; c2++) {
        int o = c2*8192 + t*16;
        int rl2 = o >> 8;
        int cb = o & 255;
        int grow = row0 + h*64 + rl2;
        if (grow < Mc)
          *(uint4*)(dst + (size_t)grow*DIM + cbase + (cb >> 1)) = *(const uint4*)((char*)Ct + o);
      }
    }
  }
}

// ---------------------------------------------------------------------------
// K6: per (f,b): h_cls row, qbase row.
__launch_bounds__(256)
__global__ void cls_gather_kernel(const float* __restrict__ hs, const float* __restrict__ hqkv,
                                  const float* __restrict__ bq,
                                  const float* __restrict__ w2, const float* __restrict__ inner_c,
                                  const int* __restrict__ gidx, const unsigned char* __restrict__ mask,
                                  const int* __restrict__ mremap,
                                  float* __restrict__ h_cls, float* __restrict__ qbase)
{
  int fb = blockIdx.x, t = threadIdx.x;
  int g0 = fb * NPOS;
  int idx = gidx[g0];
  int m = mask[g0];
  const float* q_cache = hqkv + (size_t)NC * DIM;
  __shared__ float inn[INNER_D];
  if (t < INNER_D) inn[t] = m ? inner_c[(size_t)mremap[g0]*INNER_D + t] : 0.f;
  __syncthreads();
  bool fresh = idx >= NC;
  for (int c = t; c < DIM; c += 256) {
    float hv = fresh ? hs[(size_t)(idx - NC)*DIM + c] : hqkv[(size_t)idx*DIM + c];
    float qb = fresh ? bq[c] : q_cache[(size_t)idx*DIM + c];
    if (m) {
      float hd = 0.f, qd = 0.f;
      #pragma unroll 8
      for (int j = 0; j < INNER_D; j++) {
        float iv = inn[j];
        hd += iv * w2[(size_t)j*FF + c];
        qd += iv * w2[(size_t)j*FF + DIM + c];
      }
      hv += hd; qb += qd;
    }
    h_cls[(size_t)fb*DIM + c] = hv;
    qbase[(size_t)fb*DIM + c] = qb;
  }
}

// ---------------------------------------------------------------------------
// K7: partial GEMM, M=64 fixed. grid (N/64, K/kChunk), 256 thr.
__launch_bounds__(256)
__global__ void pgemm_kernel(const float* __restrict__ X, const float* __restrict__ W,
                             float* __restrict__ part, int N, int K, int kChunk)
{
  int t = threadIdx.x;
  int c = t & 63;
  int rq = t >> 6;
  int col0 = blockIdx.x * 64;
  int k0base = blockIdx.y * kChunk;
  __shared__ __align__(16) float Xs[64][68];
  float acc[16];
  #pragma unroll
  for (int i = 0; i < 16; i++) acc[i] = 0.f;
  for (int k0 = k0base; k0 < k0base + kChunk; k0 += 64) {
    #pragma unroll
    for (int j = 0; j < 4; j++) {
      int v = t + 256*j;
      int rr = v >> 4, cc = (v & 15) << 2;
      *(float4*)&Xs[rr][cc] = *(const float4*)&X[(size_t)rr*K + k0 + cc];
    }
    __syncthreads();
    const float* Wp = W + (size_t)k0*N + col0 + c;
    #pragma unroll 4
    for (int kk = 0; kk < 64; kk += 4) {
      float w0 = Wp[(size_t)(kk+0)*N];
      float w1 = Wp[(size_t)(kk+1)*N];
      float w2 = Wp[(size_t)(kk+2)*N];
      float w3 = Wp[(size_t)(kk+3)*N];
      #pragma unroll
      for (int r = 0; r < 16; r++) {
        float4 xv = *(const float4*)&Xs[rq*16 + r][kk];
        acc[r] += xv.x*w0 + xv.y*w1 + xv.z*w2 + xv.w*w3;
      }
    }
    __syncthreads();
  }
  #pragma unroll
  for (int r = 0; r < 16; r++)
    part[((size_t)blockIdx.y*64 + rq*16 + r)*N + col0 + c] = acc[r];
}

// ---------------------------------------------------------------------------
// K8: CLS-row attention, 512 threads (8 waves), quad-dot gathers.
// q0 = (qbase + qfresh) * SCALE.
__launch_bounds__(512)
__global__ void attn_cls_kernel(const float* __restrict__ hqkv, const __bf16* __restrict__ k_newc,
                                const __bf16* __restrict__ v_newc, const float* __restrict__ w2,
                                const float* __restrict__ inner_c, const int* __restrict__ gidx,
                                const unsigned char* __restrict__ mask, const int* __restrict__ remap,
                                const int* __restrict__ mremap,
                                const float* __restrict__ qbase, const float* __restrict__ qfresh,
                                float* __restrict__ pre_cls)
{
  int bid = blockIdx.x;
  int fb = bid / NH, h = bid % NH;
  int t = threadIdx.x;
  int lane = t & 63, wv = t >> 6;
  const float* k_cache = hqkv + (size_t)2 * NC * DIM;
  const float* v_cache = hqkv + (size_t)3 * NC * DIM;
  __shared__ float q0[HD], w2q[INNER_D], tj[INNER_D];
  __shared__ float p[200];
  __shared__ int sidx[200];
  __shared__ int smg[200];
  __shared__ float red[16];
  __shared__ float pacc[8][64];
  if (t < HD) {
    size_t qoff = (size_t)fb*DIM + h*HD + t;
    q0[t] = (qbase[qoff] + qfresh[qoff]) * 0.125f;
  }
  int tt = t - 64;
  if (tt >= 0 && tt < NPOS) {
    int g = fb * NPOS + tt;
    int idx = gidx[g];
    if (idx >= NC) idx = NC + remap[idx - NC];
    sidx[tt] = idx;
    smg[tt] = mask[g] ? mremap[g] : -1;
  }
  __syncthreads();
  {
    int j = t >> 3, dg = t & 7;
    const float* wr = w2 + (size_t)j*FF + 2*DIM + h*HD + dg*8;
    float4 a = *(const float4*)wr, b = *(const float4*)(wr + 4);
    const float* q = &q0[dg*8];
    float s = a.x*q[0] + a.y*q[1] + a.z*q[2] + a.w*q[3]
            + b.x*q[4] + b.y*q[5] + b.z*q[6] + b.w*q[7];
    s += __shfl_xor(s, 1); s += __shfl_xor(s, 2); s += __shfl_xor(s, 4);
    if (dg == 0) w2q[j] = s;
  }
  __syncthreads();
  #pragma unroll
  for (int it = 0; it < 4; it++) {
    int n = it*64 + wv*8 + (lane >> 3);
    int dg = lane & 7;
    if (n < NPOS) {
      int idx = sidx[n], mg = smg[n];
      const float* q = &q0[dg*8];
      float s = 0.f;
      if (idx >= NC) {
        bf16x8 kv = *(const bf16x8*)(k_newc + (size_t)(idx - NC)*DIM + h*HD + dg*8);
        #pragma unroll
        for (int j = 0; j < 8; j++) s += q[j] * (float)kv[j];
      } else {
        const float* kr = k_cache + (size_t)idx*DIM + h*HD + dg*8;
        float4 a = *(const float4*)kr, b = *(const float4*)(kr + 4);
        s = a.x*q[0] + a.y*q[1] + a.z*q[2] + a.w*q[3]
          + b.x*q[4] + b.y*q[5] + b.z*q[6] + b.w*q[7];
      }
      if (mg >= 0) {
        const float* ir = inner_c + (size_t)mg*INNER_D + dg*8;
        float4 a = *(const float4*)ir, b = *(const float4*)(ir + 4);
        const float* wq8 = &w2q[dg*8];
        s += a.x*wq8[0] + a.y*wq8[1] + a.z*wq8[2] + a.w*wq8[3]
           + b.x*wq8[4] + b.y*wq8[5] + b.z*wq8[6] + b.w*wq8[7];
      }
      s += __shfl_xor(s, 1); s += __shfl_xor(s, 2); s += __shfl_xor(s, 4);
      if (dg == 0) p[n] = s;
    }
  }
  __syncthreads();
  float lm = (t < NPOS) ? p[t] : -1e30f;
  lm = wred_max(lm);
  if (lane == 0) red[wv] = lm;
  __syncthreads();
  float mx = red[0];
  #pragma unroll
  for (int w = 1; w < 8; w++) mx = fmaxf(mx, red[w]);
  float lp = 0.f;
  if (t < NPOS) { lp = __expf(p[t] - mx); p[t] = lp; }
  float ls = wred_sum(lp);
  if (lane == 0) red[8 + wv] = ls;
  __syncthreads();
  float inv = red[8];
  #pragma unroll
  for (int w = 1; w < 8; w++) inv += red[8 + w];
  inv = 1.0f / inv;
  float tp = 0.f;
  for (int n = wv; n < NPOS; n += 8) {
    int mg = smg[n];
    if (mg >= 0) tp += p[n] * inner_c[(size_t)mg*INNER_D + lane];
  }
  pacc[wv][lane] = tp;
  __syncthreads();
  if (t < INNER_D) tj[t] = pacc[0][t] + pacc[1][t] + pacc[2][t] + pacc[3][t]
                         + pacc[4][t] + pacc[5][t] + pacc[6][t] + pacc[7][t];
  __syncthreads();
  float va = 0.f;
  for (int n = wv; n < NPOS; n += 8) {
    float pn = p[n];
    int idx = sidx[n];
    float vvv;
    if (idx >= NC) vvv = (float)v_newc[(size_t)(idx - NC)*DIM + h*HD + lane];
    else           vvv = v_cache[(size_t)idx*DIM + h*HD + lane];
    va += pn * vvv;
  }
  __syncthreads();
  pacc[wv][lane] = va;
  __syncthreads();
  if (t < HD) {
    float o = pacc[0][t] + pacc[1][t] + pacc[2][t] + pacc[3][t]
            + pacc[4][t] + pacc[5][t] + pacc[6][t] + pacc[7][t];
    const float* wv2 = w2 + 3*DIM + h*HD + t;
    float dd = 0.f;
    for (int j = 0; j < INNER_D; j++) dd += tj[j] * wv2[(size_t)j*FF];
    pre_cls[(size_t)fb*DIM + h*HD + t] = (o + dd) * inv;
  }
}

// ---------------------------------------------------------------------------
// K9: out0 = h_cls + (sum_s partW) + bo;  yln = LN2(out0).  (12 slabs)
__launch_bounds__(256)
__global__ void reduce_wo_ln_kernel(const float* __restrict__ partW, const float* __restrict__ bo,
                                    const float* __restrict__ h_cls, const float* __restrict__ g,
                                    const float* __restrict__ b, float* __restrict__ out0,
                                    float* __restrict__ yln)
{
  int row = blockIdx.x, t = threadIdx.x;
  float v[3];
  #pragma unroll
  for (int j = 0; j < 3; j++) {
    int c = t + j*256;
    float s = h_cls[(size_t)row*DIM + c] + bo[c];
    #pragma unroll
    for (int ks = 0; ks < 12; ks++) s += partW[((size_t)ks*FB_N + row)*DIM + c];
    v[j] = s;
    out0[(size_t)row*DIM + c] = s;
  }
  float sm = wred_sum(v[0] + v[1] + v[2]);
  float sq = wred_sum(v[0]*v[0] + v[1]*v[1] + v[2]*v[2]);
  __shared__ float red[8];
  int wv = t >> 6, ln = t & 63;
  if (ln == 0) { red[wv] = sm; red[4 + wv] = sq; }
  __syncthreads();
  float mean = (red[0]+red[1]+red[2]+red[3]) * (1.f/DIM);
  float var  = (red[4]+red[5]+red[6]+red[7]) * (1.f/DIM) - mean*mean;
  float rr = rsqrtf(var + 1e-5f);
  #pragma unroll
  for (int j = 0; j < 3; j++) {
    int c = t + j*256;
    yln[(size_t)row*DIM + c] = (v[j] - mean) * rr * g[c] + b[c];
  }
}

// K10: t1 = quick_gelu(sum_s partF1 + fc1b)    (6 slabs)
__global__ void reduce_gelu_kernel(const float* __restrict__ partF1, const float* __restrict__ b1,
                                   float* __restrict__ t1)
{
  int i = blockIdx.x * 256 + threadIdx.x;   // < 196608
  int c = i % FF;
  float v = b1[c];
  #pragma unroll
  for (int s = 0; s < 6; s++) v += partF1[(size_t)s*FB_N*FF + i];
  t1[i] = v / (1.0f + __expf(-1.702f * v));
}

// K11: d_out = out0 + fc2_b + sum_s partF2     (24 slabs)
__global__ void final_reduce_kernel(const float* __restrict__ out0, const float* __restrict__ b2,
                                    const float* __restrict__ partF2, float* __restrict__ dout)
{
  int i = blockIdx.x * 256 + threadIdx.x;   // < 49152
  int c = i % DIM;
  float v = out0[i] + b2[c];
  #pragma unroll
  for (int s = 0; s < 24; s++) v += partF2[(size_t)s*FB_N*DIM + i];
  dout[i] = v;
}

// ---------------------------------------------------------------------------
extern "C" void kernel_launch(void* const* d_in, const int* in_sizes, int n_in,
                              void* d_out, int out_size, void* d_ws, size_t ws_size,
                              hipStream_t stream)
{
  const float* hs   = (const float*)d_in[0];
  const float* dpp  = (const float*)d_in[1];
  const float* hqkv = (const float*)d_in[2];
  const float* ln1g = (const float*)d_in[3];
  const float* ln1b = (const float*)d_in[4];
  const float* wq   = (const float*)d_in[5];
  const float* bq   = (const float*)d_in[6];
  const float* wk   = (const float*)d_in[7];
  const float* bk   = (const float*)d_in[8];
  const float* wvw  = (const float*)d_in[9];
  const float* bv   = (const float*)d_in[10];
  const float* w1   = (const float*)d_in[11];
  const float* w2   = (const float*)d_in[12];
  const float* wo   = (const float*)d_in[13];
  const float* bo   = (const float*)d_in[14];
  const float* ln2g = (const float*)d_in[15];
  const float* ln2b = (const float*)d_in[16];
  const float* fc1w = (const float*)d_in[17];
  const float* fc1b = (const float*)d_in[18];
  const float* fc2w = (const float*)d_in[19];
  const float* fc2b = (const float*)d_in[20];
  const int*   gidx = (const int*)d_in[21];
  const unsigned char* rmap = (const unsigned char*)d_in[22];
  float* outp = (float*)d_out;

  char* ws = (char*)d_ws;
  size_t off = 0;
  auto alloc = [&](size_t bytes) { void* p = ws + off; off += (bytes + 255) & ~(size_t)255; return p; };
  unsigned char* mask = (unsigned char*)alloc(TT);
  int* flag     = (int*)alloc((size_t)TT * 4);   // contiguous with mc: one memset
  int* mc       = (int*)alloc(256);
  int* rowlist  = (int*)alloc((size_t)TT * 4);
  int* remap    = (int*)alloc((size_t)TT * 4);
  int* mrowlist = (int*)alloc((size_t)TT * 4);
  int* mremap   = (int*)alloc((size_t)TT * 4);
  __bf16* xbf    = (__bf16*)alloc((size_t)TT * DIM * 2);
  __bf16* wcatT  = (__bf16*)alloc((size_t)NCOLS * DIM * 2);
  __bf16* wqT    = (__bf16*)alloc((size_t)DIM * DIM * 2);
  __bf16* w1T    = (__bf16*)alloc((size_t)INNER_D * DIM * 2);
  __bf16* k_newc = (__bf16*)alloc((size_t)TT * DIM * 2);
  __bf16* v_newc = (__bf16*)alloc((size_t)TT * DIM * 2);
  float* inner_c = (float*)alloc((size_t)TT * INNER_D * 4);
  float* qfresh  = (float*)alloc((size_t)FB_N * DIM * 4);
  float* h_cls  = (float*)alloc((size_t)FB_N * DIM * 4);
  float* qbase  = (float*)alloc((size_t)FB_N * DIM * 4);
  float* precls = (float*)alloc((size_t)FB_N * DIM * 4);
  float* out0   = (float*)alloc((size_t)FB_N * DIM * 4);
  float* yln    = (float*)alloc((size_t)FB_N * DIM * 4);
  float* t1     = (float*)alloc((size_t)FB_N * FF * 4);
  float* partW  = (float*)alloc((size_t)12 * FB_N * DIM * 4);
  float* partF1 = (float*)alloc((size_t)6  * FB_N * FF  * 4);
  float* partF2 = (float*)alloc((size_t)24 * FB_N * DIM * 4);
  (void)ws_size; (void)in_sizes; (void)n_in; (void)out_size;

  hipMemsetAsync(flag, 0, (size_t)TT * 4 + 256, stream);
  detect_flag_kernel<<<(TT + 255) / 256, 256, 0, stream>>>(gidx, rmap, flag, mc + 2);
  scan_kernel<<<1, 1024, 0, stream>>>(flag, rmap, mc + 2, mask, rowlist, remap,
                                      mrowlist, mremap, mc);
  stage1_kernel<<<NB_S1, 256, 0, stream>>>(wk, wvw, wq, w1, hs, ln1g, ln1b, rowlist, mc,
                                           wcatT, wqT, w1T, xbf);
  stage2_kernel<<<NB_S2, 512, 0, stream>>>(xbf, wcatT, bk, bv, dpp, w1T, wqT, mrowlist, mc,
                                           gidx, remap, k_newc, v_newc, inner_c, qfresh);
  cls_gather_kernel<<<FB_N, 256, 0, stream>>>(hs, hqkv, bq, w2, inner_c, gidx, mask,
                                              mremap, h_cls, qbase);
  attn_cls_kernel<<<FB_N * NH, 512, 0, stream>>>(hqkv, k_newc, v_newc, w2, inner_c, gidx, mask,
                                                 remap, mremap, qbase, qfresh, precls);
  // out0 = h_cls + precls@wo + bo ; yln = LN2(out0)
  pgemm_kernel<<<dim3(12, 12), 256, 0, stream>>>(precls, wo, partW, DIM, DIM, 64);
  reduce_wo_ln_kernel<<<FB_N, 256, 0, stream>>>(partW, bo, h_cls, ln2g, ln2b, out0, yln);
  // t1 = qgelu(yln@fc1w + fc1b)
  pgemm_kernel<<<dim3(48, 6), 256, 0, stream>>>(yln, fc1w, partF1, FF, DIM, 128);
  reduce_gelu_kernel<<<768, 256, 0, stream>>>(partF1, fc1b, t1);
  // d_out = out0 + t1@fc2w + fc2b
  pgemm_kernel<<<dim3(12, 24), 256, 0, stream>>>(t1, fc2w, partF2, DIM, FF, 128);
  final_reduce_kernel<<<192, 256, 0, stream>>>(out0, fc2b, partF2, outp);
}

// Round 15
// 152.671 us; speedup vs baseline: 3.8300x; 1.1575x over previous
//
#include <hip/hip_runtime.h>
#include <hip/hip_bf16.h>

// Problem constants
#define TT 12608          // 4*B*N rows of hs
#define NC 3152           // B*N cache rows (= 16*197)
#define DIM 768
#define NPOS 197
#define NH 12
#define HD 64
#define FB_N 64           // 4*B
#define FF 3072
#define INNER_D 64
#define NCOLS 1536        // K cols + V cols combined

// stage-1 block ranges (3 weight transposes: wk, wv, wq)
#define NB_TW  1728       // 24*24*3
#define NB_TW1 48         // transpose w1: 24*2
#define NB_S1  (NB_TW + NB_TW1 + TT)
// stage-2 block ranges (512 threads/block; inner first, then qfresh, then kv)
#define NB_INN 99         // ceil(TT/128)
#define NB_QF  6          // qfresh: 768/128
#define NB_KV  1248       // 8 * 13 * 12
#define NB_S2  (NB_INN + NB_QF + NB_KV)

typedef __bf16 bf16x8 __attribute__((ext_vector_type(8)));
typedef float f32x4 __attribute__((ext_vector_type(4)));

__device__ inline float wred_sum(float v){
  #pragma unroll
  for (int o = 32; o > 0; o >>= 1) v += __shfl_down(v, o, 64);
  return v;
}
__device__ inline float wred_max(float v){
  #pragma unroll
  for (int o = 32; o > 0; o >>= 1) v = fmaxf(v, __shfl_down(v, o, 64));
  return v;
}

// async global->LDS, 16B per lane
__device__ __forceinline__ void gl_lds16(const __bf16* g, __bf16* l) {
  __builtin_amdgcn_global_load_lds(
      (const __attribute__((address_space(1))) void*)g,
      (__attribute__((address_space(3))) void*)l, 16, 0, 0);
}

// ---------------------------------------------------------------------------
// K1: fused fresh-row flagging + reuse_map dtype detection.
__global__ void detect_flag_kernel(const int* __restrict__ gidx, const unsigned char* __restrict__ rm,
                                   int* __restrict__ flag, int* __restrict__ det)
{
  int g = blockIdx.x * 256 + threadIdx.x;
  int la = 0, lb = 0;
  if (g < TT) {
    int idx = gidx[g];
    if (idx >= NC) flag[idx - NC] = 1;
    unsigned char v = rm[g];
    if (v) { if (g & 3) la = 1; else lb = 1; }
  }
  unsigned long long ba = __ballot(la != 0), bb = __ballot(lb != 0);
  if ((threadIdx.x & 63) == 0) {
    if (ba) atomicOr(&det[0], 1);
    if (bb) atomicOr(&det[1], 1);
  }
}

// K1c: PARALLEL compaction via atomic chunk reservation (50 blocks).
// Compact-row ORDER is nondeterministic, but rowlist/remap stay mutually
// consistent and every downstream computation is per-row independent, so
// final outputs are bitwise identical. mc[0]/mc[1] end as the totals.
__launch_bounds__(256)
__global__ void compact_kernel(const int* __restrict__ flag, const unsigned char* __restrict__ rm,
                               const int* __restrict__ det, unsigned char* __restrict__ mask,
                               int* __restrict__ rowlist, int* __restrict__ remap,
                               int* __restrict__ mrowlist, int* __restrict__ mremap,
                               int* __restrict__ mc)
{
  __shared__ int wsumA[4], wsumB[4];
  __shared__ int baseA_s, baseB_s;
  int t = threadIdx.x, lane = t & 63, wv = t >> 6;
  int i = blockIdx.x * 256 + t;
  int mode = (!det[0]) ? 0 : (det[1] ? 1 : 2); // 0=int32, 1=byte, 2=f32
  int fA = 0, fB = 0;
  if (i < TT) {
    fA = flag[i];
    unsigned char mb_;
    if (mode == 0)      mb_ = ((const int*)rm)[i] != 0;
    else if (mode == 1) mb_ = rm[i] != 0;
    else                mb_ = ((const float*)rm)[i] != 0.0f;
    mask[i] = mb_;
    fB = mb_;
  }
  unsigned long long mbA = __ballot(fA != 0);
  unsigned long long mbB = __ballot(fB != 0);
  int rankA = __popcll(mbA & ((1ULL << lane) - 1ULL));
  int rankB = __popcll(mbB & ((1ULL << lane) - 1ULL));
  if (lane == 0) { wsumA[wv] = __popcll(mbA); wsumB[wv] = __popcll(mbB); }
  __syncthreads();
  if (t == 0) {
    int ta = wsumA[0] + wsumA[1] + wsumA[2] + wsumA[3];
    int tb = wsumB[0] + wsumB[1] + wsumB[2] + wsumB[3];
    baseA_s = ta ? atomicAdd(&mc[0], ta) : 0;
    baseB_s = tb ? atomicAdd(&mc[1], tb) : 0;
  }
  __syncthreads();
  int woffA = 0, woffB = 0;
  for (int w = 0; w < wv; w++) { woffA += wsumA[w]; woffB += wsumB[w]; }
  if (fA) { int pos = baseA_s + woffA + rankA; rowlist[pos] = i; remap[i] = pos; }
  if (fB) { int pos = baseB_s + woffB + rankB; mrowlist[pos] = i; mremap[i] = pos; }
}

// ---------------------------------------------------------------------------
// STAGE 1: fused {transpose wk/wv/wq} + {transpose w1} + {compact LN}
__launch_bounds__(256)
__global__ void stage1_kernel(const float* __restrict__ wk, const float* __restrict__ wvw,
                              const float* __restrict__ wq, const float* __restrict__ w1,
                              const float* __restrict__ hs,
                              const float* __restrict__ ln1g, const float* __restrict__ ln1b,
                              const int* __restrict__ rowlist, const int* __restrict__ mc,
                              __bf16* __restrict__ wcatT, __bf16* __restrict__ wqT,
                              __bf16* __restrict__ w1T, __bf16* __restrict__ xbf)
{
  __shared__ __align__(16) char pool[4352];
  int b = blockIdx.x, t = threadIdx.x;
  if (b < NB_TW) {
    float (*tile)[33] = (float(*)[33])pool;
    int bz = b / 576, rem = b % 576;
    int bx = rem % 24, by = rem / 24;
    int tx = t & 31, ty = t >> 5;
    const float* src = (bz == 0) ? wk : (bz == 1) ? wvw : wq;
    __bf16* dst = (bz == 0) ? wcatT : (bz == 1) ? (wcatT + (size_t)768 * DIM) : wqT;
    #pragma unroll
    for (int i = 0; i < 32; i += 8)
      tile[ty + i][tx] = src[(size_t)(by*32 + ty + i) * DIM + bx*32 + tx];
    __syncthreads();
    #pragma unroll
    for (int i = 0; i < 32; i += 8)
      dst[(size_t)(bx*32 + ty + i) * DIM + by*32 + tx] = (__bf16)tile[tx][ty + i];
    return;
  }
  if (b < NB_TW + NB_TW1) {
    float (*tile)[33] = (float(*)[33])pool;
    int rem = b - NB_TW;
    int bx = rem % 24, by = rem / 24;
    int tx = t & 31, ty = t >> 5;
    #pragma unroll
    for (int i = 0; i < 32; i += 8)
      tile[ty + i][tx] = w1[(size_t)(bx*32 + ty + i) * INNER_D + by*32 + tx];
    __syncthreads();
    #pragma unroll
    for (int i = 0; i < 32; i += 8)
      w1T[(size_t)(by*32 + ty + i) * DIM + bx*32 + tx] = (__bf16)tile[tx][ty + i];
    return;
  }
  int crow = b - NB_TW - NB_TW1;
  if (crow >= mc[0]) return;
  float* red = (float*)pool;
  int row = rowlist[crow];
  const float* x = hs + (size_t)row * DIM;
  float v0 = x[t], v1 = x[t + 256], v2 = x[t + 512];
  float s = wred_sum(v0 + v1 + v2);
  float q = wred_sum(v0*v0 + v1*v1 + v2*v2);
  int wv = t >> 6, ln = t & 63;
  if (ln == 0) { red[wv] = s; red[4 + wv] = q; }
  __syncthreads();
  float mean = (red[0]+red[1]+red[2]+red[3]) * (1.f/DIM);
  float var  = (red[4]+red[5]+red[6]+red[7]) * (1.f/DIM) - mean*mean;
  float rr = rsqrtf(var + 1e-5f);
  #pragma unroll
  for (int j = 0; j < 3; j++) {
    int c = t + j*256;
    float v = (j==0) ? v0 : (j==1) ? v1 : v2;
    xbf[(size_t)crow*DIM + c] = (__bf16)((v - mean) * rr * ln1g[c] + ln1b[c]);
  }
}

// ---------------------------------------------------------------------------
// STAGE 2 (512 threads / 8 waves): {inner GEMM 128-row tiles} + {qfresh} +
// {kv GEMM 128x128 BK=64, dbuf + counted vmcnt(4), swizzled staging, LDS-repack store}
__launch_bounds__(512)
__global__ void stage2_kernel(const __bf16* __restrict__ xbf, const __bf16* __restrict__ wcatT,
                              const float* __restrict__ bk, const float* __restrict__ bv,
                              const float* __restrict__ dpp, const __bf16* __restrict__ w1T,
                              const __bf16* __restrict__ wqT,
                              const int* __restrict__ mrowlist, const int* __restrict__ mc,
                              const int* __restrict__ gidx, const int* __restrict__ remap,
                              __bf16* __restrict__ k_newc, __bf16* __restrict__ v_newc,
                              float* __restrict__ inner_c, float* __restrict__ qfresh)
{
  __shared__ __align__(16) char pool[65536];
  int b = blockIdx.x, t = threadIdx.x;
  int lane = t & 63, wid = t >> 6;          // 8 waves
  int fr = lane & 15, fg = lane >> 4;

  if (b < NB_INN) {
    // ---- inner GEMM over MASKED rows: 128x64 tile, full K=768, gelu epilogue
    int mcnt = mc[1];
    int row0 = b * 128;
    if (row0 >= mcnt) return;
    typedef __bf16 (*tA_t)[40];
    tA_t As = (tA_t)pool;                   // [128][40]
    tA_t Bs = (tA_t)(pool + 10240);         // [64][40]
    int* rlist = (int*)(pool + 15360);      // [128]
    int wr = wid >> 1, wc = wid & 1;        // 4x2 wave grid: per-wave 32x32
    if (t < 128) rlist[t] = mrowlist[min(row0 + t, mcnt - 1)];
    __syncthreads();

    int lr = t >> 2, lc = (t & 3) << 3;     // A: 128 rows, 4 thr/row
    const float* aG = dpp + (size_t)rlist[lr] * DIM + lc;
    int lrB = (t & 255) >> 2;               // B: 64 rows (t<256 stages)
    const __bf16* bG = w1T + (size_t)lrB * DIM + lc;

    f32x4 acc[2][2];
    #pragma unroll
    for (int m = 0; m < 2; m++)
      #pragma unroll
      for (int n = 0; n < 2; n++) acc[m][n] = (f32x4){0.f, 0.f, 0.f, 0.f};

    for (int k0 = 0; k0 < DIM; k0 += 32) {
      float4 a0 = *(const float4*)(aG + k0);
      float4 a1 = *(const float4*)(aG + k0 + 4);
      bf16x8 av;
      av[0] = (__bf16)a0.x; av[1] = (__bf16)a0.y; av[2] = (__bf16)a0.z; av[3] = (__bf16)a0.w;
      av[4] = (__bf16)a1.x; av[5] = (__bf16)a1.y; av[6] = (__bf16)a1.z; av[7] = (__bf16)a1.w;
      *(bf16x8*)&As[lr][lc] = av;
      if (t < 256) *(bf16x8*)&Bs[lrB][lc] = *(const bf16x8*)(bG + k0);
      __syncthreads();
      bf16x8 af[2], bb[2];
      #pragma unroll
      for (int m = 0; m < 2; m++) af[m] = *(const bf16x8*)&As[wr*32 + m*16 + fr][fg << 3];
      #pragma unroll
      for (int n = 0; n < 2; n++) bb[n] = *(const bf16x8*)&Bs[wc*32 + n*16 + fr][fg << 3];
      #pragma unroll
      for (int m = 0; m < 2; m++)
        #pragma unroll
        for (int n = 0; n < 2; n++)
          acc[m][n] = __builtin_amdgcn_mfma_f32_16x16x32_bf16(af[m], bb[n], acc[m][n], 0, 0, 0);
      __syncthreads();
    }

    #pragma unroll
    for (int m = 0; m < 2; m++) {
      #pragma unroll
      for (int n = 0; n < 2; n++) {
        int col = wc*32 + n*16 + fr;
        int orow = row0 + wr*32 + m*16 + fg*4;
        #pragma unroll
        for (int r = 0; r < 4; r++) {
          int rr = orow + r;
          if (rr < mcnt) {
            float x = acc[m][n][r];
            float u = 0.7978845608028654f * (x + 0.044715f * x * x * x);
            inner_c[(size_t)rr*INNER_D + col] = 0.5f * x * (1.0f + tanhf(u));
          }
        }
      }
    }
    return;
  }

  if (b < NB_INN + NB_QF) {
    // ---- qfresh: 64 CLS rows @ wqT, 64x128 tile, 2x4 wave grid (per-wave 32x32)
    int col0 = (b - NB_INN) * 128;
    typedef __bf16 (*tA_t)[40];
    tA_t As = (tA_t)pool;                   // [64][40]
    tA_t Bs = (tA_t)(pool + 5632);          // [128][40]
    int* rl = (int*)(pool + 16384);
    int wr = wid >> 2, wc = wid & 3;
    if (t < FB_N) {
      int idx = gidx[t * NPOS];
      rl[t] = (idx >= NC) ? remap[idx - NC] : -1;
    }
    __syncthreads();

    f32x4 acc[2][2];
    #pragma unroll
    for (int m = 0; m < 2; m++)
      #pragma unroll
      for (int n = 0; n < 2; n++) acc[m][n] = (f32x4){0.f, 0.f, 0.f, 0.f};

    int ar = (t & 255) >> 2, ac8 = (t & 3) << 3;   // A: t<256 stages 64 rows
    int crow = (t < 256) ? rl[ar] : -1;
    int brw = t >> 2, bc8 = (t & 3) << 3;          // B: all 512 stage 128 rows
    for (int k0 = 0; k0 < DIM; k0 += 32) {
      if (t < 256) {
        bf16x8 av = {};
        if (crow >= 0) av = *(const bf16x8*)(xbf + (size_t)crow*DIM + k0 + ac8);
        *(bf16x8*)&As[ar][ac8] = av;
      }
      *(bf16x8*)&Bs[brw][bc8] = *(const bf16x8*)(wqT + (size_t)(col0 + brw)*DIM + k0 + bc8);
      __syncthreads();
      bf16x8 af[2], bb[2];
      #pragma unroll
      for (int m = 0; m < 2; m++) af[m] = *(const bf16x8*)&As[wr*32 + m*16 + fr][fg << 3];
      #pragma unroll
      for (int n = 0; n < 2; n++) bb[n] = *(const bf16x8*)&Bs[wc*32 + n*16 + fr][fg << 3];
      #pragma unroll
      for (int m = 0; m < 2; m++)
        #pragma unroll
        for (int n = 0; n < 2; n++)
          acc[m][n] = __builtin_amdgcn_mfma_f32_16x16x32_bf16(af[m], bb[n], acc[m][n], 0, 0, 0);
      __syncthreads();
    }
    #pragma unroll
    for (int m = 0; m < 2; m++) {
      #pragma unroll
      for (int n = 0; n < 2; n++) {
        int col = col0 + wc*32 + n*16 + fr;
        int row = wr*32 + m*16 + fg*4;
        #pragma unroll
        for (int r = 0; r < 4; r++)
          qfresh[(size_t)(row + r)*DIM + col] = acc[m][n][r];
      }
    }
    return;
  }

  // ---- kv GEMM: 128x128 tile, BK=64, dbuf + counted vmcnt(4), 2x4 wave grid
  {
    int Mc = mc[0];
    int npanels = (Mc + 127) >> 7;
    int b2 = b - NB_INN - NB_QF;
    int xcd = b2 & 7, s2 = b2 >> 3;
    int panel = (s2 / 12) * 8 + xcd;
    if (panel >= npanels) return;
    int col0 = (s2 % 12) * 128;
    int row0 = panel * 128;
    char* poolA0 = pool;
    char* poolA1 = pool + 16384;
    char* poolB0 = pool + 32768;
    char* poolB1 = pool + 49152;
    int wr = wid >> 2, wc = wid & 3;        // per-wave 64 rows x 32 cols

    int tr = t >> 3;
    int tc = (t & 7) << 4;
    int cbp = tc ^ ((tr & 7) << 4);         // swizzled SOURCE col
    const __bf16* aP[2];
    const __bf16* bP[2];
    #pragma unroll
    for (int c2 = 0; c2 < 2; c2++) {
      int r = c2*64 + tr;
      aP[c2] = xbf + (size_t)min(row0 + r, Mc - 1) * DIM + (cbp >> 1);
      bP[c2] = wcatT + (size_t)(col0 + r) * DIM + (cbp >> 1);
    }

    int rA[4], rB[2];
    #pragma unroll
    for (int m = 0; m < 4; m++) rA[m] = wr*64 + m*16 + fr;
    #pragma unroll
    for (int n = 0; n < 2; n++) rB[n] = wc*32 + n*16 + fr;
    int swzf = (fr & 7) << 4;

    f32x4 acc[4][2];
    #pragma unroll
    for (int m = 0; m < 4; m++)
      #pragma unroll
      for (int n = 0; n < 2; n++) acc[m][n] = (f32x4){0.f, 0.f, 0.f, 0.f};

    auto STAGE = [&](int s, char* dA, char* dB) {
      int k0 = s * 64;
      #pragma unroll
      for (int c2 = 0; c2 < 2; c2++) {
        gl_lds16(aP[c2] + k0, (__bf16*)(dA + c2*8192 + t*16));
        gl_lds16(bP[c2] + k0, (__bf16*)(dB + c2*8192 + t*16));
      }
    };

    STAGE(0, poolA0, poolB0);
    for (int s = 0; s < 12; s++) {
      char* curA = (s & 1) ? poolA1 : poolA0;
      char* curB = (s & 1) ? poolB1 : poolB0;
      if (s < 11) {
        STAGE(s + 1, (s & 1) ? poolA0 : poolA1, (s & 1) ? poolB0 : poolB1);
        asm volatile("s_waitcnt vmcnt(4)" ::: "memory");   // prev tile's 4 loads done
      } else {
        asm volatile("s_waitcnt vmcnt(0)" ::: "memory");
      }
      __builtin_amdgcn_s_barrier();
      __builtin_amdgcn_sched_barrier(0);
      #pragma unroll
      for (int kk = 0; kk < 2; kk++) {
        int co = (kk*64 + (fg << 4)) ^ swzf;
        bf16x8 af[4], bb[2];
        #pragma unroll
        for (int m = 0; m < 4; m++) af[m] = *(const bf16x8*)(curA + rA[m]*128 + co);
        #pragma unroll
        for (int n = 0; n < 2; n++) bb[n] = *(const bf16x8*)(curB + rB[n]*128 + co);
        #pragma unroll
        for (int m = 0; m < 4; m++)
          #pragma unroll
          for (int n = 0; n < 2; n++)
            acc[m][n] = __builtin_amdgcn_mfma_f32_16x16x32_bf16(af[m], bb[n], acc[m][n], 0, 0, 0);
      }
      __builtin_amdgcn_sched_barrier(0);
      __builtin_amdgcn_s_barrier();
    }

    // epilogue: per 64-row half, repack C in LDS, coalesced uint4 stores
    bool isK = (col0 < 768);
    const float* bias = isK ? bk : bv;
    __bf16* dst = isK ? k_newc : v_newc;
    int cbase = isK ? col0 : col0 - 768;
    __bf16* Ct = (__bf16*)pool;             // [64][128]
    #pragma unroll
    for (int h = 0; h < 2; h++) {
      __syncthreads();
      if (wr == h) {
        #pragma unroll
        for (int n = 0; n < 2; n++) {
          int col = wc*32 + n*16 + fr;
          float bc = bias[cbase + col];
          #pragma unroll
          for (int m = 0; m < 4; m++) {
            int rl2 = m*16 + fg*4;
            #pragma unroll
            for (int r = 0; r < 4; r++)
              Ct[(rl2 + r)*128 + col] = (__bf16)(acc[m][n][r] + bc);
          }
        }
      }
      __syncthreads();
      #pragma unroll
      for (int c2 = 0; c2 < 2; c2++) {
        int o = c2*8192 + t*16;
        int rl2 = o >> 8;
        int cb = o & 255;
        int grow = row0 + h*64 + rl2;
        if (grow < Mc)
          *(uint4*)(dst + (size_t)grow*DIM + cbase + (cb >> 1)) = *(const uint4*)((char*)Ct + o);
      }
    }
  }
}

// ---------------------------------------------------------------------------
// K6: per (f,b): h_cls row, qbase row.
__launch_bounds__(256)
__global__ void cls_gather_kernel(const float* __restrict__ hs, const float* __restrict__ hqkv,
                                  const float* __restrict__ bq,
                                  const float* __restrict__ w2, const float* __restrict__ inner_c,
                                  const int* __restrict__ gidx, const unsigned char* __restrict__ mask,
                                  const int* __restrict__ mremap,
                                  float* __restrict__ h_cls, float* __restrict__ qbase)
{
  int fb = blockIdx.x, t = threadIdx.x;
  int g0 = fb * NPOS;
  int idx = gidx[g0];
  int m = mask[g0];
  const float* q_cache = hqkv + (size_t)NC * DIM;
  __shared__ float inn[INNER_D];
  if (t < INNER_D) inn[t] = m ? inner_c[(size_t)mremap[g0]*INNER_D + t] : 0.f;
  __syncthreads();
  bool fresh = idx >= NC;
  for (int c = t; c < DIM; c += 256) {
    float hv = fresh ? hs[(size_t)(idx - NC)*DIM + c] : hqkv[(size_t)idx*DIM + c];
    float qb = fresh ? bq[c] : q_cache[(size_t)idx*DIM + c];
    if (m) {
      float hd = 0.f, qd = 0.f;
      #pragma unroll 8
      for (int j = 0; j < INNER_D; j++) {
        float iv = inn[j];
        hd += iv * w2[(size_t)j*FF + c];
        qd += iv * w2[(size_t)j*FF + DIM + c];
      }
      hv += hd; qb += qd;
    }
    h_cls[(size_t)fb*DIM + c] = hv;
    qbase[(size_t)fb*DIM + c] = qb;
  }
}

// ---------------------------------------------------------------------------
// K7: partial GEMM, M=64 fixed. grid (N/64, K/kChunk), 256 thr.
// 16-deep independent W loads per group to hide HBM/L2 latency.
__launch_bounds__(256)
__global__ void pgemm_kernel(const float* __restrict__ X, const float* __restrict__ W,
                             float* __restrict__ part, int N, int K, int kChunk)
{
  int t = threadIdx.x;
  int c = t & 63;
  int rq = t >> 6;
  int col0 = blockIdx.x * 64;
  int k0base = blockIdx.y * kChunk;
  __shared__ __align__(16) float Xs[64][68];
  float acc[16];
  #pragma unroll
  for (int i = 0; i < 16; i++) acc[i] = 0.f;
  for (int k0 = k0base; k0 < k0base + kChunk; k0 += 64) {
    #pragma unroll
    for (int j = 0; j < 4; j++) {
      int v = t + 256*j;
      int rr = v >> 4, cc = (v & 15) << 2;
      *(float4*)&Xs[rr][cc] = *(const float4*)&X[(size_t)rr*K + k0 + cc];
    }
    __syncthreads();
    const float* Wp = W + (size_t)k0*N + col0 + c;
    #pragma unroll
    for (int kk0 = 0; kk0 < 64; kk0 += 16) {
      float w[16];
      #pragma unroll
      for (int u = 0; u < 16; u++) w[u] = Wp[(size_t)(kk0 + u)*N];
      #pragma unroll
      for (int u = 0; u < 16; u += 4) {
        #pragma unroll
        for (int r = 0; r < 16; r++) {
          float4 xv = *(const float4*)&Xs[rq*16 + r][kk0 + u];
          acc[r] += xv.x*w[u] + xv.y*w[u+1] + xv.z*w[u+2] + xv.w*w[u+3];
        }
      }
    }
    __syncthreads();
  }
  #pragma unroll
  for (int r = 0; r < 16; r++)
    part[((size_t)blockIdx.y*64 + rq*16 + r)*N + col0 + c] = acc[r];
}

// ---------------------------------------------------------------------------
// K8: CLS-row attention, 512 threads (8 waves), quad-dot gathers.
// q0 = (qbase + qfresh) * SCALE.
__launch_bounds__(512)
__global__ void attn_cls_kernel(const float* __restrict__ hqkv, const __bf16* __restrict__ k_newc,
                                const __bf16* __restrict__ v_newc, const float* __restrict__ w2,
                                const float* __restrict__ inner_c, const int* __restrict__ gidx,
                                const unsigned char* __restrict__ mask, const int* __restrict__ remap,
                                const int* __restrict__ mremap,
                                const float* __restrict__ qbase, const float* __restrict__ qfresh,
                                float* __restrict__ pre_cls)
{
  int bid = blockIdx.x;
  int fb = bid / NH, h = bid % NH;
  int t = threadIdx.x;
  int lane = t & 63, wv = t >> 6;
  const float* k_cache = hqkv + (size_t)2 * NC * DIM;
  const float* v_cache = hqkv + (size_t)3 * NC * DIM;
  __shared__ float q0[HD], w2q[INNER_D], tj[INNER_D];
  __shared__ float p[200];
  __shared__ int sidx[200];
  __shared__ int smg[200];
  __shared__ float red[16];
  __shared__ float pacc[8][64];
  if (t < HD) {
    size_t qoff = (size_t)fb*DIM + h*HD + t;
    q0[t] = (qbase[qoff] + qfresh[qoff]) * 0.125f;
  }
  int tt = t - 64;
  if (tt >= 0 && tt < NPOS) {
    int g = fb * NPOS + tt;
    int idx = gidx[g];
    if (idx >= NC) idx = NC + remap[idx - NC];
    sidx[tt] = idx;
    smg[tt] = mask[g] ? mremap[g] : -1;
  }
  __syncthreads();
  {
    int j = t >> 3, dg = t & 7;
    const float* wr = w2 + (size_t)j*FF + 2*DIM + h*HD + dg*8;
    float4 a = *(const float4*)wr, b = *(const float4*)(wr + 4);
    const float* q = &q0[dg*8];
    float s = a.x*q[0] + a.y*q[1] + a.z*q[2] + a.w*q[3]
            + b.x*q[4] + b.y*q[5] + b.z*q[6] + b.w*q[7];
    s += __shfl_xor(s, 1); s += __shfl_xor(s, 2); s += __shfl_xor(s, 4);
    if (dg == 0) w2q[j] = s;
  }
  __syncthreads();
  #pragma unroll
  for (int it = 0; it < 4; it++) {
    int n = it*64 + wv*8 + (lane >> 3);
    int dg = lane & 7;
    if (n < NPOS) {
      int idx = sidx[n], mg = smg[n];
      const float* q = &q0[dg*8];
      float s = 0.f;
      if (idx >= NC) {
        bf16x8 kv = *(const bf16x8*)(k_newc + (size_t)(idx - NC)*DIM + h*HD + dg*8);
        #pragma unroll
        for (int j = 0; j < 8; j++) s += q[j] * (float)kv[j];
      } else {
        const float* kr = k_cache + (size_t)idx*DIM + h*HD + dg*8;
        float4 a = *(const float4*)kr, b = *(const float4*)(kr + 4);
        s = a.x*q[0] + a.y*q[1] + a.z*q[2] + a.w*q[3]
          + b.x*q[4] + b.y*q[5] + b.z*q[6] + b.w*q[7];
      }
      if (mg >= 0) {
        const float* ir = inner_c + (size_t)mg*INNER_D + dg*8;
        float4 a = *(const float4*)ir, b = *(const float4*)(ir + 4);
        const float* wq8 = &w2q[dg*8];
        s += a.x*wq8[0] + a.y*wq8[1] + a.z*wq8[2] + a.w*wq8[3]
           + b.x*wq8[4] + b.y*wq8[5] + b.z*wq8[6] + b.w*wq8[7];
      }
      s += __shfl_xor(s, 1); s += __shfl_xor(s, 2); s += __shfl_xor(s, 4);
      if (dg == 0) p[n] = s;
    }
  }
  __syncthreads();
  float lm = (t < NPOS) ? p[t] : -1e30f;
  lm = wred_max(lm);
  if (lane == 0) red[wv] = lm;
  __syncthreads();
  float mx = red[0];
  #pragma unroll
  for (int w = 1; w < 8; w++) mx = fmaxf(mx, red[w]);
  float lp = 0.f;
  if (t < NPOS) { lp = __expf(p[t] - mx); p[t] = lp; }
  float ls = wred_sum(lp);
  if (lane == 0) red[8 + wv] = ls;
  __syncthreads();
  float inv = red[8];
  #pragma unroll
  for (int w = 1; w < 8; w++) inv += red[8 + w];
  inv = 1.0f / inv;
  float tp = 0.f;
  for (int n = wv; n < NPOS; n += 8) {
    int mg = smg[n];
    if (mg >= 0) tp += p[n] * inner_c[(size_t)mg*INNER_D + lane];
  }
  pacc[wv][lane] = tp;
  __syncthreads();
  if (t < INNER_D) tj[t] = pacc[0][t] + pacc[1][t] + pacc[2][t] + pacc[3][t]
                         + pacc[4][t] + pacc[5][t] + pacc[6][t] + pacc[7][t];
  __syncthreads();
  float va = 0.f;
  for (int n = wv; n < NPOS; n += 8) {
    float pn = p[n];
    int idx = sidx[n];
    float vvv;
    if (idx >= NC) vvv = (float)v_newc[(size_t)(idx - NC)*DIM + h*HD + lane];
    else           vvv = v_cache[(size_t)idx*DIM + h*HD + lane];
    va += pn * vvv;
  }
  __syncthreads();
  pacc[wv][lane] = va;
  __syncthreads();
  if (t < HD) {
    float o = pacc[0][t] + pacc[1][t] + pacc[2][t] + pacc[3][t]
            + pacc[4][t] + pacc[5][t] + pacc[6][t] + pacc[7][t];
    const float* wv2 = w2 + 3*DIM + h*HD + t;
    float dd = 0.f;
    for (int j = 0; j < INNER_D; j++) dd += tj[j] * wv2[(size_t)j*FF];
    pre_cls[(size_t)fb*DIM + h*HD + t] = (o + dd) * inv;
  }
}

// ---------------------------------------------------------------------------
// K9: out0 = h_cls + (sum_s partW) + bo;  yln = LN2(out0).  (12 slabs)
__launch_bounds__(256)
__global__ void reduce_wo_ln_kernel(const float* __restrict__ partW, const float* __restrict__ bo,
                                    const float* __restrict__ h_cls, const float* __restrict__ g,
                                    const float* __restrict__ b, float* __restrict__ out0,
                                    float* __restrict__ yln)
{
  int row = blockIdx.x, t = threadIdx.x;
  float v[3];
  #pragma unroll
  for (int j = 0; j < 3; j++) {
    int c = t + j*256;
    float s = h_cls[(size_t)row*DIM + c] + bo[c];
    #pragma unroll
    for (int ks = 0; ks < 12; ks++) s += partW[((size_t)ks*FB_N + row)*DIM + c];
    v[j] = s;
    out0[(size_t)row*DIM + c] = s;
  }
  float sm = wred_sum(v[0] + v[1] + v[2]);
  float sq = wred_sum(v[0]*v[0] + v[1]*v[1] + v[2]*v[2]);
  __shared__ float red[8];
  int wv = t >> 6, ln = t & 63;
  if (ln == 0) { red[wv] = sm; red[4 + wv] = sq; }
  __syncthreads();
  float mean = (red[0]+red[1]+red[2]+red[3]) * (1.f/DIM);
  float var  = (red[4]+red[5]+red[6]+red[7]) * (1.f/DIM) - mean*mean;
  float rr = rsqrtf(var + 1e-5f);
  #pragma unroll
  for (int j = 0; j < 3; j++) {
    int c = t + j*256;
    yln[(size_t)row*DIM + c] = (v[j] - mean) * rr * g[c] + b[c];
  }
}

// K10: t1 = quick_gelu(sum_s partF1 + fc1b)    (6 slabs)
__global__ void reduce_gelu_kernel(const float* __restrict__ partF1, const float* __restrict__ b1,
                                   float* __restrict__ t1)
{
  int i = blockIdx.x * 256 + threadIdx.x;   // < 196608
  int c = i % FF;
  float v = b1[c];
  #pragma unroll
  for (int s = 0; s < 6; s++) v += partF1[(size_t)s*FB_N*FF + i];
  t1[i] = v / (1.0f + __expf(-1.702f * v));
}

// K11: d_out = out0 + fc2_b + sum_s partF2     (24 slabs)
__global__ void final_reduce_kernel(const float* __restrict__ out0, const float* __restrict__ b2,
                                    const float* __restrict__ partF2, float* __restrict__ dout)
{
  int i = blockIdx.x * 256 + threadIdx.x;   // < 49152
  int c = i % DIM;
  float v = out0[i] + b2[c];
  #pragma unroll
  for (int s = 0; s < 24; s++) v += partF2[(size_t)s*FB_N*DIM + i];
  dout[i] = v;
}

// ---------------------------------------------------------------------------
extern "C" void kernel_launch(void* const* d_in, const int* in_sizes, int n_in,
                              void* d_out, int out_size, void* d_ws, size_t ws_size,
                              hipStream_t stream)
{
  const float* hs   = (const float*)d_in[0];
  const float* dpp  = (const float*)d_in[1];
  const float* hqkv = (const float*)d_in[2];
  const float* ln1g = (const float*)d_in[3];
  const float* ln1b = (const float*)d_in[4];
  const float* wq   = (const float*)d_in[5];
  const float* bq   = (const float*)d_in[6];
  const float* wk   = (const float*)d_in[7];
  const float* bk   = (const float*)d_in[8];
  const float* wvw  = (const float*)d_in[9];
  const float* bv   = (const float*)d_in[10];
  const float* w1   = (const float*)d_in[11];
  const float* w2   = (const float*)d_in[12];
  const float* wo   = (const float*)d_in[13];
  const float* bo   = (const float*)d_in[14];
  const float* ln2g = (const float*)d_in[15];
  const float* ln2b = (const float*)d_in[16];
  const float* fc1w = (const float*)d_in[17];
  const float* fc1b = (const float*)d_in[18];
  const float* fc2w = (const float*)d_in[19];
  const float* fc2b = (const float*)d_in[20];
  const int*   gidx = (const int*)d_in[21];
  const unsigned char* rmap = (const unsigned char*)d_in[22];
  float* outp = (float*)d_out;

  char* ws = (char*)d_ws;
  size_t off = 0;
  auto alloc = [&](size_t bytes) { void* p = ws + off; off += (bytes + 255) & ~(size_t)255; return p; };
  unsigned char* mask = (unsigned char*)alloc(TT);
  int* flag     = (int*)alloc((size_t)TT * 4);   // contiguous with mc: one memset
  int* mc       = (int*)alloc(256);              // mc[0]/mc[1]=atomic counters, mc[2..3]=detect
  int* rowlist  = (int*)alloc((size_t)TT * 4);
  int* remap    = (int*)alloc((size_t)TT * 4);
  int* mrowlist = (int*)alloc((size_t)TT * 4);
  int* mremap   = (int*)alloc((size_t)TT * 4);
  __bf16* xbf    = (__bf16*)alloc((size_t)TT * DIM * 2);
  __bf16* wcatT  = (__bf16*)alloc((size_t)NCOLS * DIM * 2);
  __bf16* wqT    = (__bf16*)alloc((size_t)DIM * DIM * 2);
  __bf16* w1T    = (__bf16*)alloc((size_t)INNER_D * DIM * 2);
  __bf16* k_newc = (__bf16*)alloc((size_t)TT * DIM * 2);
  __bf16* v_newc = (__bf16*)alloc((size_t)TT * DIM * 2);
  float* inner_c = (float*)alloc((size_t)TT * INNER_D * 4);
  float* qfresh  = (float*)alloc((size_t)FB_N * DIM * 4);
  float* h_cls  = (float*)alloc((size_t)FB_N * DIM * 4);
  float* qbase  = (float*)alloc((size_t)FB_N * DIM * 4);
  float* precls = (float*)alloc((size_t)FB_N * DIM * 4);
  float* out0   = (float*)alloc((size_t)FB_N * DIM * 4);
  float* yln    = (float*)alloc((size_t)FB_N * DIM * 4);
  float* t1     = (float*)alloc((size_t)FB_N * FF * 4);
  float* partW  = (float*)alloc((size_t)12 * FB_N * DIM * 4);
  float* partF1 = (float*)alloc((size_t)6  * FB_N * FF  * 4);
  float* partF2 = (float*)alloc((size_t)24 * FB_N * DIM * 4);
  (void)ws_size; (void)in_sizes; (void)n_in; (void)out_size;

  hipMemsetAsync(flag, 0, (size_t)TT * 4 + 256, stream);
  detect_flag_kernel<<<(TT + 255) / 256, 256, 0, stream>>>(gidx, rmap, flag, mc + 2);
  compact_kernel<<<(TT + 255) / 256, 256, 0, stream>>>(flag, rmap, mc + 2, mask,
                                                       rowlist, remap, mrowlist, mremap, mc);
  stage1_kernel<<<NB_S1, 256, 0, stream>>>(wk, wvw, wq, w1, hs, ln1g, ln1b, rowlist, mc,
                                           wcatT, wqT, w1T, xbf);
  stage2_kernel<<<NB_S2, 512, 0, stream>>>(xbf, wcatT, bk, bv, dpp, w1T, wqT, mrowlist, mc,
                                           gidx, remap, k_newc, v_newc, inner_c, qfresh);
  cls_gather_kernel<<<FB_N, 256, 0, stream>>>(hs, hqkv, bq, w2, inner_c, gidx, mask,
                                              mremap, h_cls, qbase);
  attn_cls_kernel<<<FB_N * NH, 512, 0, stream>>>(hqkv, k_newc, v_newc, w2, inner_c, gidx, mask,
                                                 remap, mremap, qbase, qfresh, precls);
  // out0 = h_cls + precls@wo + bo ; yln = LN2(out0)
  pgemm_kernel<<<dim3(12, 12), 256, 0, stream>>>(precls, wo, partW, DIM, DIM, 64);
  reduce_wo_ln_kernel<<<FB_N, 256, 0, stream>>>(partW, bo, h_cls, ln2g, ln2b, out0, yln);
  // t1 = qgelu(yln@fc1w + fc1b)
  pgemm_kernel<<<dim3(48, 6), 256, 0, stream>>>(yln, fc1w, partF1, FF, DIM, 128);
  reduce_gelu_kernel<<<768, 256, 0, stream>>>(partF1, fc1b, t1);
  // d_out = out0 + t1@fc2w + fc2b
  pgemm_kernel<<<dim3(12, 24), 256, 0, stream>>>(t1, fc2w, partF2, DIM, FF, 128);
  final_reduce_kernel<<<192, 256, 0, stream>>>(out0, fc2b, partF2, outp);
}

// Round 16
// 151.077 us; speedup vs baseline: 3.8704x; 1.0106x over previous
//
#include <hip/hip_runtime.h>
#include <hip/hip_bf16.h>

// Problem constants
#define TT 12608          // 4*B*N rows of hs
#define NC 3152           // B*N cache rows (= 16*197)
#define DIM 768
#define NPOS 197
#define NH 12
#define HD 64
#define FB_N 64           // 4*B
#define FF 3072
#define INNER_D 64
#define NCOLS 1536        // K cols + V cols combined

// stage-1 block ranges (3 weight transposes: wk, wv, wq)
#define NB_TW  1728       // 24*24*3
#define NB_TW1 48         // transpose w1: 24*2
#define NB_S1  (NB_TW + NB_TW1 + TT)
// stage-2 block ranges (512 threads/block; inner first, then qfresh, then kv)
#define NB_INN 99         // ceil(TT/128)
#define NB_QF  6          // qfresh: 768/128
#define NB_KV  624        // 8 XCD * 13 panel-slots * 6 col-tiles(256 wide)
#define NB_S2  (NB_INN + NB_QF + NB_KV)

typedef __bf16 bf16x8 __attribute__((ext_vector_type(8)));
typedef float f32x4 __attribute__((ext_vector_type(4)));

__device__ inline float wred_sum(float v){
  #pragma unroll
  for (int o = 32; o > 0; o >>= 1) v += __shfl_down(v, o, 64);
  return v;
}
__device__ inline float wred_max(float v){
  #pragma unroll
  for (int o = 32; o > 0; o >>= 1) v = fmaxf(v, __shfl_down(v, o, 64));
  return v;
}

// async global->LDS, 16B per lane
__device__ __forceinline__ void gl_lds16(const __bf16* g, __bf16* l) {
  __builtin_amdgcn_global_load_lds(
      (const __attribute__((address_space(1))) void*)g,
      (__attribute__((address_space(3))) void*)l, 16, 0, 0);
}

// ---------------------------------------------------------------------------
// K1: fused fresh-row flagging + reuse_map dtype detection.
__global__ void detect_flag_kernel(const int* __restrict__ gidx, const unsigned char* __restrict__ rm,
                                   int* __restrict__ flag, int* __restrict__ det)
{
  int g = blockIdx.x * 256 + threadIdx.x;
  int la = 0, lb = 0;
  if (g < TT) {
    int idx = gidx[g];
    if (idx >= NC) flag[idx - NC] = 1;
    unsigned char v = rm[g];
    if (v) { if (g & 3) la = 1; else lb = 1; }
  }
  unsigned long long ba = __ballot(la != 0), bb = __ballot(lb != 0);
  if ((threadIdx.x & 63) == 0) {
    if (ba) atomicOr(&det[0], 1);
    if (bb) atomicOr(&det[1], 1);
  }
}

// K1c: PARALLEL compaction via atomic chunk reservation (50 blocks).
__launch_bounds__(256)
__global__ void compact_kernel(const int* __restrict__ flag, const unsigned char* __restrict__ rm,
                               const int* __restrict__ det, unsigned char* __restrict__ mask,
                               int* __restrict__ rowlist, int* __restrict__ remap,
                               int* __restrict__ mrowlist, int* __restrict__ mremap,
                               int* __restrict__ mc)
{
  __shared__ int wsumA[4], wsumB[4];
  __shared__ int baseA_s, baseB_s;
  int t = threadIdx.x, lane = t & 63, wv = t >> 6;
  int i = blockIdx.x * 256 + t;
  int mode = (!det[0]) ? 0 : (det[1] ? 1 : 2); // 0=int32, 1=byte, 2=f32
  int fA = 0, fB = 0;
  if (i < TT) {
    fA = flag[i];
    unsigned char mb_;
    if (mode == 0)      mb_ = ((const int*)rm)[i] != 0;
    else if (mode == 1) mb_ = rm[i] != 0;
    else                mb_ = ((const float*)rm)[i] != 0.0f;
    mask[i] = mb_;
    fB = mb_;
  }
  unsigned long long mbA = __ballot(fA != 0);
  unsigned long long mbB = __ballot(fB != 0);
  int rankA = __popcll(mbA & ((1ULL << lane) - 1ULL));
  int rankB = __popcll(mbB & ((1ULL << lane) - 1ULL));
  if (lane == 0) { wsumA[wv] = __popcll(mbA); wsumB[wv] = __popcll(mbB); }
  __syncthreads();
  if (t == 0) {
    int ta = wsumA[0] + wsumA[1] + wsumA[2] + wsumA[3];
    int tb = wsumB[0] + wsumB[1] + wsumB[2] + wsumB[3];
    baseA_s = ta ? atomicAdd(&mc[0], ta) : 0;
    baseB_s = tb ? atomicAdd(&mc[1], tb) : 0;
  }
  __syncthreads();
  int woffA = 0, woffB = 0;
  for (int w = 0; w < wv; w++) { woffA += wsumA[w]; woffB += wsumB[w]; }
  if (fA) { int pos = baseA_s + woffA + rankA; rowlist[pos] = i; remap[i] = pos; }
  if (fB) { int pos = baseB_s + woffB + rankB; mrowlist[pos] = i; mremap[i] = pos; }
}

// ---------------------------------------------------------------------------
// STAGE 1: fused {transpose wk/wv/wq} + {transpose w1} + {compact LN}
__launch_bounds__(256)
__global__ void stage1_kernel(const float* __restrict__ wk, const float* __restrict__ wvw,
                              const float* __restrict__ wq, const float* __restrict__ w1,
                              const float* __restrict__ hs,
                              const float* __restrict__ ln1g, const float* __restrict__ ln1b,
                              const int* __restrict__ rowlist, const int* __restrict__ mc,
                              __bf16* __restrict__ wcatT, __bf16* __restrict__ wqT,
                              __bf16* __restrict__ w1T, __bf16* __restrict__ xbf)
{
  __shared__ __align__(16) char pool[4352];
  int b = blockIdx.x, t = threadIdx.x;
  if (b < NB_TW) {
    float (*tile)[33] = (float(*)[33])pool;
    int bz = b / 576, rem = b % 576;
    int bx = rem % 24, by = rem / 24;
    int tx = t & 31, ty = t >> 5;
    const float* src = (bz == 0) ? wk : (bz == 1) ? wvw : wq;
    __bf16* dst = (bz == 0) ? wcatT : (bz == 1) ? (wcatT + (size_t)768 * DIM) : wqT;
    #pragma unroll
    for (int i = 0; i < 32; i += 8)
      tile[ty + i][tx] = src[(size_t)(by*32 + ty + i) * DIM + bx*32 + tx];
    __syncthreads();
    #pragma unroll
    for (int i = 0; i < 32; i += 8)
      dst[(size_t)(bx*32 + ty + i) * DIM + by*32 + tx] = (__bf16)tile[tx][ty + i];
    return;
  }
  if (b < NB_TW + NB_TW1) {
    float (*tile)[33] = (float(*)[33])pool;
    int rem = b - NB_TW;
    int bx = rem % 24, by = rem / 24;
    int tx = t & 31, ty = t >> 5;
    #pragma unroll
    for (int i = 0; i < 32; i += 8)
      tile[ty + i][tx] = w1[(size_t)(bx*32 + ty + i) * INNER_D + by*32 + tx];
    __syncthreads();
    #pragma unroll
    for (int i = 0; i < 32; i += 8)
      w1T[(size_t)(by*32 + ty + i) * DIM + bx*32 + tx] = (__bf16)tile[tx][ty + i];
    return;
  }
  int crow = b - NB_TW - NB_TW1;
  if (crow >= mc[0]) return;
  float* red = (float*)pool;
  int row = rowlist[crow];
  const float* x = hs + (size_t)row * DIM;
  float v0 = x[t], v1 = x[t + 256], v2 = x[t + 512];
  float s = wred_sum(v0 + v1 + v2);
  float q = wred_sum(v0*v0 + v1*v1 + v2*v2);
  int wv = t >> 6, ln = t & 63;
  if (ln == 0) { red[wv] = s; red[4 + wv] = q; }
  __syncthreads();
  float mean = (red[0]+red[1]+red[2]+red[3]) * (1.f/DIM);
  float var  = (red[4]+red[5]+red[6]+red[7]) * (1.f/DIM) - mean*mean;
  float rr = rsqrtf(var + 1e-5f);
  #pragma unroll
  for (int j = 0; j < 3; j++) {
    int c = t + j*256;
    float v = (j==0) ? v0 : (j==1) ? v1 : v2;
    xbf[(size_t)crow*DIM + c] = (__bf16)((v - mean) * rr * ln1g[c] + ln1b[c]);
  }
}

// ---------------------------------------------------------------------------
// STAGE 2 (512 threads / 8 waves): {inner GEMM 128-row tiles} + {qfresh} +
// {kv GEMM 128x256 tile, BK=32, dbuf + counted vmcnt(3), granule-swizzled LDS,
//  LDS-repack coalesced C-store}
__launch_bounds__(512)
__global__ void stage2_kernel(const __bf16* __restrict__ xbf, const __bf16* __restrict__ wcatT,
                              const float* __restrict__ bk, const float* __restrict__ bv,
                              const float* __restrict__ dpp, const __bf16* __restrict__ w1T,
                              const __bf16* __restrict__ wqT,
                              const int* __restrict__ mrowlist, const int* __restrict__ mc,
                              const int* __restrict__ gidx, const int* __restrict__ remap,
                              __bf16* __restrict__ k_newc, __bf16* __restrict__ v_newc,
                              float* __restrict__ inner_c, float* __restrict__ qfresh)
{
  __shared__ __align__(16) char pool[49152];
  int b = blockIdx.x, t = threadIdx.x;
  int lane = t & 63, wid = t >> 6;          // 8 waves
  int fr = lane & 15, fg = lane >> 4;

  if (b < NB_INN) {
    // ---- inner GEMM over MASKED rows: 128x64 tile, full K=768, gelu epilogue
    int mcnt = mc[1];
    int row0 = b * 128;
    if (row0 >= mcnt) return;
    typedef __bf16 (*tA_t)[40];
    tA_t As = (tA_t)pool;                   // [128][40]
    tA_t Bs = (tA_t)(pool + 10240);         // [64][40]
    int* rlist = (int*)(pool + 15360);      // [128]
    int wr = wid >> 1, wc = wid & 1;        // 4x2 wave grid: per-wave 32x32
    if (t < 128) rlist[t] = mrowlist[min(row0 + t, mcnt - 1)];
    __syncthreads();

    int lr = t >> 2, lc = (t & 3) << 3;
    const float* aG = dpp + (size_t)rlist[lr] * DIM + lc;
    int lrB = (t & 255) >> 2;
    const __bf16* bG = w1T + (size_t)lrB * DIM + lc;

    f32x4 acc[2][2];
    #pragma unroll
    for (int m = 0; m < 2; m++)
      #pragma unroll
      for (int n = 0; n < 2; n++) acc[m][n] = (f32x4){0.f, 0.f, 0.f, 0.f};

    for (int k0 = 0; k0 < DIM; k0 += 32) {
      float4 a0 = *(const float4*)(aG + k0);
      float4 a1 = *(const float4*)(aG + k0 + 4);
      bf16x8 av;
      av[0] = (__bf16)a0.x; av[1] = (__bf16)a0.y; av[2] = (__bf16)a0.z; av[3] = (__bf16)a0.w;
      av[4] = (__bf16)a1.x; av[5] = (__bf16)a1.y; av[6] = (__bf16)a1.z; av[7] = (__bf16)a1.w;
      *(bf16x8*)&As[lr][lc] = av;
      if (t < 256) *(bf16x8*)&Bs[lrB][lc] = *(const bf16x8*)(bG + k0);
      __syncthreads();
      bf16x8 af[2], bb[2];
      #pragma unroll
      for (int m = 0; m < 2; m++) af[m] = *(const bf16x8*)&As[wr*32 + m*16 + fr][fg << 3];
      #pragma unroll
      for (int n = 0; n < 2; n++) bb[n] = *(const bf16x8*)&Bs[wc*32 + n*16 + fr][fg << 3];
      #pragma unroll
      for (int m = 0; m < 2; m++)
        #pragma unroll
        for (int n = 0; n < 2; n++)
          acc[m][n] = __builtin_amdgcn_mfma_f32_16x16x32_bf16(af[m], bb[n], acc[m][n], 0, 0, 0);
      __syncthreads();
    }

    #pragma unroll
    for (int m = 0; m < 2; m++) {
      #pragma unroll
      for (int n = 0; n < 2; n++) {
        int col = wc*32 + n*16 + fr;
        int orow = row0 + wr*32 + m*16 + fg*4;
        #pragma unroll
        for (int r = 0; r < 4; r++) {
          int rr = orow + r;
          if (rr < mcnt) {
            float x = acc[m][n][r];
            float u = 0.7978845608028654f * (x + 0.044715f * x * x * x);
            inner_c[(size_t)rr*INNER_D + col] = 0.5f * x * (1.0f + tanhf(u));
          }
        }
      }
    }
    return;
  }

  if (b < NB_INN + NB_QF) {
    // ---- qfresh: 64 CLS rows @ wqT, 64x128 tile, 2x4 wave grid (per-wave 32x32)
    int col0 = (b - NB_INN) * 128;
    typedef __bf16 (*tA_t)[40];
    tA_t As = (tA_t)pool;                   // [64][40]
    tA_t Bs = (tA_t)(pool + 5632);          // [128][40]
    int* rl = (int*)(pool + 16384);
    int wr = wid >> 2, wc = wid & 3;
    if (t < FB_N) {
      int idx = gidx[t * NPOS];
      rl[t] = (idx >= NC) ? remap[idx - NC] : -1;
    }
    __syncthreads();

    f32x4 acc[2][2];
    #pragma unroll
    for (int m = 0; m < 2; m++)
      #pragma unroll
      for (int n = 0; n < 2; n++) acc[m][n] = (f32x4){0.f, 0.f, 0.f, 0.f};

    int ar = (t & 255) >> 2, ac8 = (t & 3) << 3;
    int crow = (t < 256) ? rl[ar] : -1;
    int brw = t >> 2, bc8 = (t & 3) << 3;
    for (int k0 = 0; k0 < DIM; k0 += 32) {
      if (t < 256) {
        bf16x8 av = {};
        if (crow >= 0) av = *(const bf16x8*)(xbf + (size_t)crow*DIM + k0 + ac8);
        *(bf16x8*)&As[ar][ac8] = av;
      }
      *(bf16x8*)&Bs[brw][bc8] = *(const bf16x8*)(wqT + (size_t)(col0 + brw)*DIM + k0 + bc8);
      __syncthreads();
      bf16x8 af[2], bb[2];
      #pragma unroll
      for (int m = 0; m < 2; m++) af[m] = *(const bf16x8*)&As[wr*32 + m*16 + fr][fg << 3];
      #pragma unroll
      for (int n = 0; n < 2; n++) bb[n] = *(const bf16x8*)&Bs[wc*32 + n*16 + fr][fg << 3];
      #pragma unroll
      for (int m = 0; m < 2; m++)
        #pragma unroll
        for (int n = 0; n < 2; n++)
          acc[m][n] = __builtin_amdgcn_mfma_f32_16x16x32_bf16(af[m], bb[n], acc[m][n], 0, 0, 0);
      __syncthreads();
    }
    #pragma unroll
    for (int m = 0; m < 2; m++) {
      #pragma unroll
      for (int n = 0; n < 2; n++) {
        int col = col0 + wc*32 + n*16 + fr;
        int row = wr*32 + m*16 + fg*4;
        #pragma unroll
        for (int r = 0; r < 4; r++)
          qfresh[(size_t)(row + r)*DIM + col] = acc[m][n][r];
      }
    }
    return;
  }

  // ---- kv GEMM: 128x256 tile, BK=32, dbuf + counted vmcnt(3), 2x4 wave grid
  // (per-wave 64x64 = 4x4 frags). LDS rows are 64B; granule swizzle:
  //   stored[r][g] = orig[r][g ^ ((r>>1)&3)]  (g = 16B granule, 4 per row)
  // read granule = fg ^ ((fr>>1)&3)  (independent of m/n/wave offsets).
  {
    int Mc = mc[0];
    int npanels = (Mc + 127) >> 7;
    int b2 = b - NB_INN - NB_QF;
    int xcd = b2 & 7, s2 = b2 >> 3;         // s2 = panel-slot*6 + coltile
    int panel = (s2 / 6) * 8 + xcd;
    if (panel >= npanels) return;
    int col0 = (s2 % 6) * 256;              // 256-wide: tiles 0-2 K, 3-5 V
    int row0 = panel * 128;
    char* buf0 = pool;                      // stage: A 8KB + B 16KB = 24KB
    char* buf1 = pool + 24576;
    int wr = wid >> 2, wc = wid & 3;        // per-wave 64 rows x 64 cols

    // staging addresses (pre-swizzled source granule)
    int srow = t >> 2;                       // 0..127
    int gsrc = (t & 3) ^ ((t >> 3) & 3);     // swizzled source granule
    int scol = gsrc << 3;                    // element col within 32
    const __bf16* aP = xbf + (size_t)min(row0 + srow, Mc - 1) * DIM + scol;
    const __bf16* bP0 = wcatT + (size_t)(col0 + srow) * DIM + scol;
    const __bf16* bP1 = wcatT + (size_t)(col0 + 128 + srow) * DIM + scol;

    int rA[4], rB[4];
    #pragma unroll
    for (int m = 0; m < 4; m++) rA[m] = wr*64 + m*16 + fr;
    #pragma unroll
    for (int n = 0; n < 4; n++) rB[n] = wc*64 + n*16 + fr;
    int co16 = (fg ^ ((fr >> 1) & 3)) << 4;  // swizzled read byte offset

    f32x4 acc[4][4];
    #pragma unroll
    for (int m = 0; m < 4; m++)
      #pragma unroll
      for (int n = 0; n < 4; n++) acc[m][n] = (f32x4){0.f, 0.f, 0.f, 0.f};

    auto STAGE = [&](int s, char* d) {
      int k0 = s * 32;
      gl_lds16(aP + k0, (__bf16*)(d + t*16));                 // A: [128][32] = 8KB
      gl_lds16(bP0 + k0, (__bf16*)(d + 8192 + t*16));         // B rows 0..127
      gl_lds16(bP1 + k0, (__bf16*)(d + 16384 + t*16));        // B rows 128..255
    };

    STAGE(0, buf0);
    for (int s = 0; s < 24; s++) {
      char* cur = (s & 1) ? buf1 : buf0;
      if (s < 23) {
        STAGE(s + 1, (s & 1) ? buf0 : buf1);
        asm volatile("s_waitcnt vmcnt(3)" ::: "memory");   // current stage resident
      } else {
        asm volatile("s_waitcnt vmcnt(0)" ::: "memory");
      }
      __builtin_amdgcn_s_barrier();
      __builtin_amdgcn_sched_barrier(0);
      char* curA = cur;
      char* curB = cur + 8192;
      bf16x8 af[4], bb[4];
      #pragma unroll
      for (int m = 0; m < 4; m++) af[m] = *(const bf16x8*)(curA + rA[m]*64 + co16);
      #pragma unroll
      for (int n = 0; n < 4; n++) bb[n] = *(const bf16x8*)(curB + rB[n]*64 + co16);
      #pragma unroll
      for (int m = 0; m < 4; m++)
        #pragma unroll
        for (int n = 0; n < 4; n++)
          acc[m][n] = __builtin_amdgcn_mfma_f32_16x16x32_bf16(af[m], bb[n], acc[m][n], 0, 0, 0);
      __builtin_amdgcn_sched_barrier(0);
      __builtin_amdgcn_s_barrier();
    }

    // epilogue: per 64-row half, repack C (64x256 bf16 = 32KB) in LDS,
    // coalesced uint4 stores.
    bool isK = (col0 < 768);
    const float* bias = isK ? bk : bv;
    __bf16* dst = isK ? k_newc : v_newc;
    int cbase = isK ? col0 : col0 - 768;
    __bf16* Ct = (__bf16*)pool;             // [64][256]
    #pragma unroll
    for (int h = 0; h < 2; h++) {
      __syncthreads();
      if (wr == h) {
        #pragma unroll
        for (int n = 0; n < 4; n++) {
          int col = wc*64 + n*16 + fr;
          float bc = bias[cbase + col];
          #pragma unroll
          for (int m = 0; m < 4; m++) {
            int rl2 = m*16 + fg*4;
            #pragma unroll
            for (int r = 0; r < 4; r++)
              Ct[(rl2 + r)*256 + col] = (__bf16)(acc[m][n][r] + bc);
          }
        }
      }
      __syncthreads();
      #pragma unroll
      for (int c2 = 0; c2 < 4; c2++) {
        int o = c2*8192 + t*16;
        int rl2 = o >> 9;                   // 512 B per Ct row
        int cb = o & 511;
        int grow = row0 + h*64 + rl2;
        if (grow < Mc)
          *(uint4*)(dst + (size_t)grow*DIM + cbase + (cb >> 1)) = *(const uint4*)((char*)Ct + o);
      }
    }
  }
}

// ---------------------------------------------------------------------------
// K6: per (f,b): h_cls row, qbase row.
__launch_bounds__(256)
__global__ void cls_gather_kernel(const float* __restrict__ hs, const float* __restrict__ hqkv,
                                  const float* __restrict__ bq,
                                  const float* __restrict__ w2, const float* __restrict__ inner_c,
                                  const int* __restrict__ gidx, const unsigned char* __restrict__ mask,
                                  const int* __restrict__ mremap,
                                  float* __restrict__ h_cls, float* __restrict__ qbase)
{
  int fb = blockIdx.x, t = threadIdx.x;
  int g0 = fb * NPOS;
  int idx = gidx[g0];
  int m = mask[g0];
  const float* q_cache = hqkv + (size_t)NC * DIM;
  __shared__ float inn[INNER_D];
  if (t < INNER_D) inn[t] = m ? inner_c[(size_t)mremap[g0]*INNER_D + t] : 0.f;
  __syncthreads();
  bool fresh = idx >= NC;
  for (int c = t; c < DIM; c += 256) {
    float hv = fresh ? hs[(size_t)(idx - NC)*DIM + c] : hqkv[(size_t)idx*DIM + c];
    float qb = fresh ? bq[c] : q_cache[(size_t)idx*DIM + c];
    if (m) {
      float hd = 0.f, qd = 0.f;
      #pragma unroll 8
      for (int j = 0; j < INNER_D; j++) {
        float iv = inn[j];
        hd += iv * w2[(size_t)j*FF + c];
        qd += iv * w2[(size_t)j*FF + DIM + c];
      }
      hv += hd; qb += qd;
    }
    h_cls[(size_t)fb*DIM + c] = hv;
    qbase[(size_t)fb*DIM + c] = qb;
  }
}

// ---------------------------------------------------------------------------
// K7: partial GEMM, M=64 fixed. grid (N/64, K/kChunk), 256 thr.
// 16-deep independent W loads per group to hide HBM/L2 latency.
__launch_bounds__(256)
__global__ void pgemm_kernel(const float* __restrict__ X, const float* __restrict__ W,
                             float* __restrict__ part, int N, int K, int kChunk)
{
  int t = threadIdx.x;
  int c = t & 63;
  int rq = t >> 6;
  int col0 = blockIdx.x * 64;
  int k0base = blockIdx.y * kChunk;
  __shared__ __align__(16) float Xs[64][68];
  float acc[16];
  #pragma unroll
  for (int i = 0; i < 16; i++) acc[i] = 0.f;
  for (int k0 = k0base; k0 < k0base + kChunk; k0 += 64) {
    #pragma unroll
    for (int j = 0; j < 4; j++) {
      int v = t + 256*j;
      int rr = v >> 4, cc = (v & 15) << 2;
      *(float4*)&Xs[rr][cc] = *(const float4*)&X[(size_t)rr*K + k0 + cc];
    }
    __syncthreads();
    const float* Wp = W + (size_t)k0*N + col0 + c;
    #pragma unroll
    for (int kk0 = 0; kk0 < 64; kk0 += 16) {
      float w[16];
      #pragma unroll
      for (int u = 0; u < 16; u++) w[u] = Wp[(size_t)(kk0 + u)*N];
      #pragma unroll
      for (int u = 0; u < 16; u += 4) {
        #pragma unroll
        for (int r = 0; r < 16; r++) {
          float4 xv = *(const float4*)&Xs[rq*16 + r][kk0 + u];
          acc[r] += xv.x*w[u] + xv.y*w[u+1] + xv.z*w[u+2] + xv.w*w[u+3];
        }
      }
    }
    __syncthreads();
  }
  #pragma unroll
  for (int r = 0; r < 16; r++)
    part[((size_t)blockIdx.y*64 + rq*16 + r)*N + col0 + c] = acc[r];
}

// ---------------------------------------------------------------------------
// K8: CLS-row attention, 512 threads (8 waves), quad-dot gathers.
// q0 = (qbase + qfresh) * SCALE.
__launch_bounds__(512)
__global__ void attn_cls_kernel(const float* __restrict__ hqkv, const __bf16* __restrict__ k_newc,
                                const __bf16* __restrict__ v_newc, const float* __restrict__ w2,
                                const float* __restrict__ inner_c, const int* __restrict__ gidx,
                                const unsigned char* __restrict__ mask, const int* __restrict__ remap,
                                const int* __restrict__ mremap,
                                const float* __restrict__ qbase, const float* __restrict__ qfresh,
                                float* __restrict__ pre_cls)
{
  int bid = blockIdx.x;
  int fb = bid / NH, h = bid % NH;
  int t = threadIdx.x;
  int lane = t & 63, wv = t >> 6;
  const float* k_cache = hqkv + (size_t)2 * NC * DIM;
  const float* v_cache = hqkv + (size_t)3 * NC * DIM;
  __shared__ float q0[HD], w2q[INNER_D], tj[INNER_D];
  __shared__ float p[200];
  __shared__ int sidx[200];
  __shared__ int smg[200];
  __shared__ float red[16];
  __shared__ float pacc[8][64];
  if (t < HD) {
    size_t qoff = (size_t)fb*DIM + h*HD + t;
    q0[t] = (qbase[qoff] + qfresh[qoff]) * 0.125f;
  }
  int tt = t - 64;
  if (tt >= 0 && tt < NPOS) {
    int g = fb * NPOS + tt;
    int idx = gidx[g];
    if (idx >= NC) idx = NC + remap[idx - NC];
    sidx[tt] = idx;
    smg[tt] = mask[g] ? mremap[g] : -1;
  }
  __syncthreads();
  {
    int j = t >> 3, dg = t & 7;
    const float* wr = w2 + (size_t)j*FF + 2*DIM + h*HD + dg*8;
    float4 a = *(const float4*)wr, b = *(const float4*)(wr + 4);
    const float* q = &q0[dg*8];
    float s = a.x*q[0] + a.y*q[1] + a.z*q[2] + a.w*q[3]
            + b.x*q[4] + b.y*q[5] + b.z*q[6] + b.w*q[7];
    s += __shfl_xor(s, 1); s += __shfl_xor(s, 2); s += __shfl_xor(s, 4);
    if (dg == 0) w2q[j] = s;
  }
  __syncthreads();
  #pragma unroll
  for (int it = 0; it < 4; it++) {
    int n = it*64 + wv*8 + (lane >> 3);
    int dg = lane & 7;
    if (n < NPOS) {
      int idx = sidx[n], mg = smg[n];
      const float* q = &q0[dg*8];
      float s = 0.f;
      if (idx >= NC) {
        bf16x8 kv = *(const bf16x8*)(k_newc + (size_t)(idx - NC)*DIM + h*HD + dg*8);
        #pragma unroll
        for (int j = 0; j < 8; j++) s += q[j] * (float)kv[j];
      } else {
        const float* kr = k_cache + (size_t)idx*DIM + h*HD + dg*8;
        float4 a = *(const float4*)kr, b = *(const float4*)(kr + 4);
        s = a.x*q[0] + a.y*q[1] + a.z*q[2] + a.w*q[3]
          + b.x*q[4] + b.y*q[5] + b.z*q[6] + b.w*q[7];
      }
      if (mg >= 0) {
        const float* ir = inner_c + (size_t)mg*INNER_D + dg*8;
        float4 a = *(const float4*)ir, b = *(const float4*)(ir + 4);
        const float* wq8 = &w2q[dg*8];
        s += a.x*wq8[0] + a.y*wq8[1] + a.z*wq8[2] + a.w*wq8[3]
           + b.x*wq8[4] + b.y*wq8[5] + b.z*wq8[6] + b.w*wq8[7];
      }
      s += __shfl_xor(s, 1); s += __shfl_xor(s, 2); s += __shfl_xor(s, 4);
      if (dg == 0) p[n] = s;
    }
  }
  __syncthreads();
  float lm = (t < NPOS) ? p[t] : -1e30f;
  lm = wred_max(lm);
  if (lane == 0) red[wv] = lm;
  __syncthreads();
  float mx = red[0];
  #pragma unroll
  for (int w = 1; w < 8; w++) mx = fmaxf(mx, red[w]);
  float lp = 0.f;
  if (t < NPOS) { lp = __expf(p[t] - mx); p[t] = lp; }
  float ls = wred_sum(lp);
  if (lane == 0) red[8 + wv] = ls;
  __syncthreads();
  float inv = red[8];
  #pragma unroll
  for (int w = 1; w < 8; w++) inv += red[8 + w];
  inv = 1.0f / inv;
  float tp = 0.f;
  for (int n = wv; n < NPOS; n += 8) {
    int mg = smg[n];
    if (mg >= 0) tp += p[n] * inner_c[(size_t)mg*INNER_D + lane];
  }
  pacc[wv][lane] = tp;
  __syncthreads();
  if (t < INNER_D) tj[t] = pacc[0][t] + pacc[1][t] + pacc[2][t] + pacc[3][t]
                         + pacc[4][t] + pacc[5][t] + pacc[6][t] + pacc[7][t];
  __syncthreads();
  float va = 0.f;
  for (int n = wv; n < NPOS; n += 8) {
    float pn = p[n];
    int idx = sidx[n];
    float vvv;
    if (idx >= NC) vvv = (float)v_newc[(size_t)(idx - NC)*DIM + h*HD + lane];
    else           vvv = v_cache[(size_t)idx*DIM + h*HD + lane];
    va += pn * vvv;
  }
  __syncthreads();
  pacc[wv][lane] = va;
  __syncthreads();
  if (t < HD) {
    float o = pacc[0][t] + pacc[1][t] + pacc[2][t] + pacc[3][t]
            + pacc[4][t] + pacc[5][t] + pacc[6][t] + pacc[7][t];
    const float* wv2 = w2 + 3*DIM + h*HD + t;
    float dd = 0.f;
    for (int j = 0; j < INNER_D; j++) dd += tj[j] * wv2[(size_t)j*FF];
    pre_cls[(size_t)fb*DIM + h*HD + t] = (o + dd) * inv;
  }
}

// ---------------------------------------------------------------------------
// K9: out0 = h_cls + (sum_s partW) + bo;  yln = LN2(out0).  (12 slabs)
__launch_bounds__(256)
__global__ void reduce_wo_ln_kernel(const float* __restrict__ partW, const float* __restrict__ bo,
                                    const float* __restrict__ h_cls, const float* __restrict__ g,
                                    const float* __restrict__ b, float* __restrict__ out0,
                                    float* __restrict__ yln)
{
  int row = blockIdx.x, t = threadIdx.x;
  float v[3];
  #pragma unroll
  for (int j = 0; j < 3; j++) {
    int c = t + j*256;
    float s = h_cls[(size_t)row*DIM + c] + bo[c];
    #pragma unroll
    for (int ks = 0; ks < 12; ks++) s += partW[((size_t)ks*FB_N + row)*DIM + c];
    v[j] = s;
    out0[(size_t)row*DIM + c] = s;
  }
  float sm = wred_sum(v[0] + v[1] + v[2]);
  float sq = wred_sum(v[0]*v[0] + v[1]*v[1] + v[2]*v[2]);
  __shared__ float red[8];
  int wv = t >> 6, ln = t & 63;
  if (ln == 0) { red[wv] = sm; red[4 + wv] = sq; }
  __syncthreads();
  float mean = (red[0]+red[1]+red[2]+red[3]) * (1.f/DIM);
  float var  = (red[4]+red[5]+red[6]+red[7]) * (1.f/DIM) - mean*mean;
  float rr = rsqrtf(var + 1e-5f);
  #pragma unroll
  for (int j = 0; j < 3; j++) {
    int c = t + j*256;
    yln[(size_t)row*DIM + c] = (v[j] - mean) * rr * g[c] + b[c];
  }
}

// K10: t1 = quick_gelu(sum_s partF1 + fc1b)    (6 slabs)
__global__ void reduce_gelu_kernel(const float* __restrict__ partF1, const float* __restrict__ b1,
                                   float* __restrict__ t1)
{
  int i = blockIdx.x * 256 + threadIdx.x;   // < 196608
  int c = i % FF;
  float v = b1[c];
  #pragma unroll
  for (int s = 0; s < 6; s++) v += partF1[(size_t)s*FB_N*FF + i];
  t1[i] = v / (1.0f + __expf(-1.702f * v));
}

// K11: d_out = out0 + fc2_b + sum_s partF2     (24 slabs)
__global__ void final_reduce_kernel(const float* __restrict__ out0, const float* __restrict__ b2,
                                    const float* __restrict__ partF2, float* __restrict__ dout)
{
  int i = blockIdx.x * 256 + threadIdx.x;   // < 49152
  int c = i % DIM;
  float v = out0[i] + b2[c];
  #pragma unroll
  for (int s = 0; s < 24; s++) v += partF2[(size_t)s*FB_N*DIM + i];
  dout[i] = v;
}

// ---------------------------------------------------------------------------
extern "C" void kernel_launch(void* const* d_in, const int* in_sizes, int n_in,
                              void* d_out, int out_size, void* d_ws, size_t ws_size,
                              hipStream_t stream)
{
  const float* hs   = (const float*)d_in[0];
  const float* dpp  = (const float*)d_in[1];
  const float* hqkv = (const float*)d_in[2];
  const float* ln1g = (const float*)d_in[3];
  const float* ln1b = (const float*)d_in[4];
  const float* wq   = (const float*)d_in[5];
  const float* bq   = (const float*)d_in[6];
  const float* wk   = (const float*)d_in[7];
  const float* bk   = (const float*)d_in[8];
  const float* wvw  = (const float*)d_in[9];
  const float* bv   = (const float*)d_in[10];
  const float* w1   = (const float*)d_in[11];
  const float* w2   = (const float*)d_in[12];
  const float* wo   = (const float*)d_in[13];
  const float* bo   = (const float*)d_in[14];
  const float* ln2g = (const float*)d_in[15];
  const float* ln2b = (const float*)d_in[16];
  const float* fc1w = (const float*)d_in[17];
  const float* fc1b = (const float*)d_in[18];
  const float* fc2w = (const float*)d_in[19];
  const float* fc2b = (const float*)d_in[20];
  const int*   gidx = (const int*)d_in[21];
  const unsigned char* rmap = (const unsigned char*)d_in[22];
  float* outp = (float*)d_out;

  char* ws = (char*)d_ws;
  size_t off = 0;
  auto alloc = [&](size_t bytes) { void* p = ws + off; off += (bytes + 255) & ~(size_t)255; return p; };
  unsigned char* mask = (unsigned char*)alloc(TT);
  int* flag     = (int*)alloc((size_t)TT * 4);   // contiguous with mc: one memset
  int* mc       = (int*)alloc(256);              // mc[0]/mc[1]=atomic counters, mc[2..3]=detect
  int* rowlist  = (int*)alloc((size_t)TT * 4);
  int* remap    = (int*)alloc((size_t)TT * 4);
  int* mrowlist = (int*)alloc((size_t)TT * 4);
  int* mremap   = (int*)alloc((size_t)TT * 4);
  __bf16* xbf    = (__bf16*)alloc((size_t)TT * DIM * 2);
  __bf16* wcatT  = (__bf16*)alloc((size_t)NCOLS * DIM * 2);
  __bf16* wqT    = (__bf16*)alloc((size_t)DIM * DIM * 2);
  __bf16* w1T    = (__bf16*)alloc((size_t)INNER_D * DIM * 2);
  __bf16* k_newc = (__bf16*)alloc((size_t)TT * DIM * 2);
  __bf16* v_newc = (__bf16*)alloc((size_t)TT * DIM * 2);
  float* inner_c = (float*)alloc((size_t)TT * INNER_D * 4);
  float* qfresh  = (float*)alloc((size_t)FB_N * DIM * 4);
  float* h_cls  = (float*)alloc((size_t)FB_N * DIM * 4);
  float* qbase  = (float*)alloc((size_t)FB_N * DIM * 4);
  float* precls = (float*)alloc((size_t)FB_N * DIM * 4);
  float* out0   = (float*)alloc((size_t)FB_N * DIM * 4);
  float* yln    = (float*)alloc((size_t)FB_N * DIM * 4);
  float* t1     = (float*)alloc((size_t)FB_N * FF * 4);
  float* partW  = (float*)alloc((size_t)12 * FB_N * DIM * 4);
  float* partF1 = (float*)alloc((size_t)6  * FB_N * FF  * 4);
  float* partF2 = (float*)alloc((size_t)24 * FB_N * DIM * 4);
  (void)ws_size; (void)in_sizes; (void)n_in; (void)out_size;

  hipMemsetAsync(flag, 0, (size_t)TT * 4 + 256, stream);
  detect_flag_kernel<<<(TT + 255) / 256, 256, 0, stream>>>(gidx, rmap, flag, mc + 2);
  compact_kernel<<<(TT + 255) / 256, 256, 0, stream>>>(flag, rmap, mc + 2, mask,
                                                       rowlist, remap, mrowlist, mremap, mc);
  stage1_kernel<<<NB_S1, 256, 0, stream>>>(wk, wvw, wq, w1, hs, ln1g, ln1b, rowlist, mc,
                                           wcatT, wqT, w1T, xbf);
  stage2_kernel<<<NB_S2, 512, 0, stream>>>(xbf, wcatT, bk, bv, dpp, w1T, wqT, mrowlist, mc,
                                           gidx, remap, k_newc, v_newc, inner_c, qfresh);
  cls_gather_kernel<<<FB_N, 256, 0, stream>>>(hs, hqkv, bq, w2, inner_c, gidx, mask,
                                              mremap, h_cls, qbase);
  attn_cls_kernel<<<FB_N * NH, 512, 0, stream>>>(hqkv, k_newc, v_newc, w2, inner_c, gidx, mask,
                                                 remap, mremap, qbase, qfresh, precls);
  // out0 = h_cls + precls@wo + bo ; yln = LN2(out0)
  pgemm_kernel<<<dim3(12, 12), 256, 0, stream>>>(precls, wo, partW, DIM, DIM, 64);
  reduce_wo_ln_kernel<<<FB_N, 256, 0, stream>>>(partW, bo, h_cls, ln2g, ln2b, out0, yln);
  // t1 = qgelu(yln@fc1w + fc1b)
  pgemm_kernel<<<dim3(48, 6), 256, 0, stream>>>(yln, fc1w, partF1, FF, DIM, 128);
  reduce_gelu_kernel<<<768, 256, 0, stream>>>(partF1, fc1b, t1);
  // d_out = out0 + t1@fc2w + fc2b
  pgemm_kernel<<<dim3(12, 24), 256, 0, stream>>>(t1, fc2w, partF2, DIM, FF, 128);
  final_reduce_kernel<<<192, 256, 0, stream>>>(out0, fc2b, partF2, outp);
}